// Round 8
// baseline (639.213 us; speedup 1.0000x reference)
//
#include <hip/hip_runtime.h>

#define S 2048
#define D 2048
#define H 16
#define HD 128
#define N3 6144  // 3*D

typedef __attribute__((ext_vector_type(8))) short bf16x8;
typedef __attribute__((ext_vector_type(4))) float f32x4;
typedef __attribute__((ext_vector_type(16))) float f32x16;
typedef unsigned short ushort_t;
typedef unsigned int uint_t;

// ---------------------------------------------------------------------------
// bf16 split helpers (round-to-nearest-even)
// ---------------------------------------------------------------------------
__device__ __forceinline__ ushort_t bf16_rne(float f) {
    uint_t u = __float_as_uint(f);
    u += 0x7fffu + ((u >> 16) & 1u);
    return (ushort_t)(u >> 16);
}
__device__ __forceinline__ float bf16_f32(ushort_t h) {
    return __uint_as_float(((uint_t)h) << 16);
}

// split f32 row-major -> hi/lo bf16 row-major (same layout)
__global__ __launch_bounds__(256) void convert_split_kernel(
    const float* __restrict__ in, ushort_t* __restrict__ hi,
    ushort_t* __restrict__ lo)
{
    const int i = blockIdx.x * 256 + threadIdx.x;  // per float4
    float4 v = ((const float4*)in)[i];
    ushort_t h0 = bf16_rne(v.x), h1 = bf16_rne(v.y);
    ushort_t h2 = bf16_rne(v.z), h3 = bf16_rne(v.w);
    ushort4 hv = make_ushort4(h0, h1, h2, h3);
    ushort4 lv = make_ushort4(bf16_rne(v.x - bf16_f32(h0)),
                              bf16_rne(v.y - bf16_f32(h1)),
                              bf16_rne(v.z - bf16_f32(h2)),
                              bf16_rne(v.w - bf16_f32(h3)));
    ((ushort4*)hi)[i] = hv;
    ((ushort4*)lo)[i] = lv;
}

// W [K][N] f32 -> Wt hi/lo [N][K] bf16 (transpose + split), 32x32 tiles.
__global__ __launch_bounds__(256) void convert_split_t_kernel(
    const float* __restrict__ in, ushort_t* __restrict__ hi,
    ushort_t* __restrict__ lo, int Kdim, int Ndim)
{
    __shared__ float tile[32][33];
    const int k0 = blockIdx.x * 32, n0 = blockIdx.y * 32;
    const int tx = threadIdx.x & 31, ty = threadIdx.x >> 5;  // ty 0..7
    #pragma unroll
    for (int r = 0; r < 4; r++)
        tile[ty + r * 8][tx] = in[(size_t)(k0 + ty + r * 8) * Ndim + n0 + tx];
    __syncthreads();
    const int n  = threadIdx.x >> 3;        // 0..31 local col
    const int kc = (threadIdx.x & 7) * 4;   // 0..28 local k chunk
    const float v0 = tile[kc + 0][n], v1 = tile[kc + 1][n];
    const float v2 = tile[kc + 2][n], v3 = tile[kc + 3][n];
    const ushort_t h0 = bf16_rne(v0), h1 = bf16_rne(v1);
    const ushort_t h2 = bf16_rne(v2), h3 = bf16_rne(v3);
    const size_t off = (size_t)(n0 + n) * Kdim + k0 + kc;
    *(ushort4*)&hi[off] = make_ushort4(h0, h1, h2, h3);
    *(ushort4*)&lo[off] = make_ushort4(bf16_rne(v0 - bf16_f32(h0)),
                                       bf16_rne(v1 - bf16_f32(h1)),
                                       bf16_rne(v2 - bf16_f32(h2)),
                                       bf16_rne(v3 - bf16_f32(h3)));
}

// ---------------------------------------------------------------------------
// async global->LDS, 16 B per lane, wave-uniform LDS base (HW adds lane*16).
// ---------------------------------------------------------------------------
__device__ __forceinline__ void gload16(const ushort_t* g, ushort_t* l) {
    __builtin_amdgcn_global_load_lds(
        (const __attribute__((address_space(1))) unsigned int*)g,
        (__attribute__((address_space(3))) unsigned int*)l, 16, 0, 0);
}

// ---------------------------------------------------------------------------
// Split-bf16 MFMA GEMM core, R8: BK=16, mfma_f32_32x32x16_bf16, dbuf 32 KB
// -> 4 blocks/CU. LDS rows interleave hi|lo (64 B rows: 2-way banks, free).
// Per wave-iter: 8 ds_read_b128 + 12 MFMA (3-term: Ah*Bh + Ah*Bl + Al*Bh).
// Staging: per-lane source addressing does the h|l interleave; dest stays
// the contiguous wave-uniform-base layout global_load_lds requires.
// ---------------------------------------------------------------------------
#define BK16 16
#define BUF_ELEMS 8192   // A-combined 4096 + B-combined 4096 elems (16 KB)

__device__ __forceinline__ void mm_core_split(
    const ushort_t* __restrict__ Agh, const ushort_t* __restrict__ Agl,
    const ushort_t* __restrict__ Bgh, const ushort_t* __restrict__ Bgl,
    const int K, ushort_t* lds, const int t, f32x16 (&acc)[2][2])
{
    const int lane = t & 63;
    const int wv   = t >> 6;
    const int srow = lane >> 2;          // 0..15 local staging row
    const int part = lane & 3;           // 0,1 -> hi ; 2,3 -> lo
    const int poff = (part & 1) * 8;     // elem offset within 16-elem half
    const int col  = lane & 31;
    const int half = lane >> 5;          // k-half: k = half*8 + j
    const int wm   = (wv & 1) * 64;
    const int wn   = (wv >> 1) * 64;

    auto stage = [&](int k0, int buf) {
        ushort_t* Ab = lds + buf * BUF_ELEMS;
        ushort_t* Bb = Ab + 4096;
        #pragma unroll
        for (int j = 0; j < 2; j++) {
            const int r = j * 64 + wv * 16 + srow;
            const int dst = (j * 64 + wv * 16) * 32;  // elems (64 B rows)
            const ushort_t* asrc =
                ((part < 2) ? Agh : Agl) + (size_t)r * K + k0 + poff;
            gload16(asrc, Ab + dst);
            const ushort_t* bsrc =
                ((part < 2) ? Bgh : Bgl) + (size_t)r * K + k0 + poff;
            gload16(bsrc, Bb + dst);
        }
    };

    stage(0, 0);

    const int niter = K / BK16;
    for (int it = 0; it < niter; it++) {
        const int cur = it & 1;
        __syncthreads();  // drains vmcnt: tile it visible; buf cur^1 free

        if (it + 1 < niter) stage((it + 1) * BK16, cur ^ 1);

        ushort_t* Ab = lds + cur * BUF_ELEMS;
        ushort_t* Bb = Ab + 4096;

        bf16x8 af_h[2], af_l[2], bf_h[2], bf_l[2];
        #pragma unroll
        for (int i = 0; i < 2; i++) {
            const int arow = (wm + i * 32 + col) * 32 + half * 8;
            af_h[i] = *(const bf16x8*)&Ab[arow];
            af_l[i] = *(const bf16x8*)&Ab[arow + 16];
            const int brow = (wn + i * 32 + col) * 32 + half * 8;
            bf_h[i] = *(const bf16x8*)&Bb[brow];
            bf_l[i] = *(const bf16x8*)&Bb[brow + 16];
        }
        #pragma unroll
        for (int mt = 0; mt < 2; mt++)
            #pragma unroll
            for (int nt = 0; nt < 2; nt++) {
                acc[mt][nt] = __builtin_amdgcn_mfma_f32_32x32x16_bf16(
                    af_h[mt], bf_h[nt], acc[mt][nt], 0, 0, 0);
                acc[mt][nt] = __builtin_amdgcn_mfma_f32_32x32x16_bf16(
                    af_h[mt], bf_l[nt], acc[mt][nt], 0, 0, 0);
                acc[mt][nt] = __builtin_amdgcn_mfma_f32_32x32x16_bf16(
                    af_l[mt], bf_h[nt], acc[mt][nt], 0, 0, 0);
            }
    }
}

// C/D layout for 32x32 (verified m74/m101): col = lane&31,
// row = (reg&3) + 4*(lane>>5) + 8*(reg>>2), reg in [0,16).

// ---------------------------------------------------------------------------
// QKV GEMM (MFMA) with split-bf16 outputs; 32x32 C-layout epilogue.
// ---------------------------------------------------------------------------
__global__ __launch_bounds__(256, 4) void gemm_qkv_mfma(
    const ushort_t* __restrict__ xh, const ushort_t* __restrict__ xl,
    const ushort_t* __restrict__ Wth, const ushort_t* __restrict__ Wtl,
    const float* __restrict__ bias, const float* __restrict__ freqs,
    const int* __restrict__ input_pos,
    ushort_t* __restrict__ qhg, ushort_t* __restrict__ qlg,
    ushort_t* __restrict__ khg, ushort_t* __restrict__ klg,
    ushort_t* __restrict__ vhg, ushort_t* __restrict__ vlg)
{
    __shared__ ushort_t lds[2 * BUF_ELEMS];   // 32 KB
    const int t = threadIdx.x;
    const int col0 = blockIdx.x * 128;
    const int row0 = blockIdx.y * 128;

    f32x16 acc[2][2] = {};
    mm_core_split(xh + (size_t)row0 * D, xl + (size_t)row0 * D,
                  Wth + (size_t)col0 * D, Wtl + (size_t)col0 * D,
                  D, lds, t, acc);

    const int lane = t & 63;
    const int col  = lane & 31;
    const int half = lane >> 5;
    const int wm = ((t >> 6) & 1) * 64;
    const int wn = ((t >> 6) >> 1) * 64;

    const int which = col0 >> 11;           // 0=q 1=k 2=v
    const int hh = (col0 & 2047) >> 7;

    if (which == 2) {
        ushort_t* vh_b = vhg + (size_t)hh * HD * S;
        ushort_t* vl_b = vlg + (size_t)hh * HD * S;
        #pragma unroll
        for (int nt = 0; nt < 2; nt++) {
            const int d = wn + nt * 32 + col;
            const float bsc = bias[col0 + d];
            #pragma unroll
            for (int mt = 0; mt < 2; mt++) {
                #pragma unroll
                for (int reg = 0; reg < 16; reg++) {
                    const int m = row0 + wm + mt * 32 +
                                  (reg & 3) + 4 * half + 8 * (reg >> 2);
                    const float v = acc[mt][nt][reg] + bsc;
                    const ushort_t hv = bf16_rne(v);
                    const ushort_t lv = bf16_rne(v - bf16_f32(hv));
                    const int pos = input_pos[m];
                    vh_b[(size_t)d * S + pos] = hv;
                    vl_b[(size_t)d * S + pos] = lv;
                }
            }
        }
    } else {
        ushort_t* oh_b = ((which == 0) ? qhg : khg) + (size_t)hh * S * HD;
        ushort_t* ol_b = ((which == 0) ? qlg : klg) + (size_t)hh * S * HD;
        #pragma unroll
        for (int nt = 0; nt < 2; nt++) {
            const int d = wn + nt * 32 + col;
            const float bsc = bias[col0 + d];
            #pragma unroll
            for (int mt = 0; mt < 2; mt++) {
                #pragma unroll
                for (int reg = 0; reg < 16; reg++) {
                    const int m = row0 + wm + mt * 32 +
                                  (reg & 3) + 4 * half + 8 * (reg >> 2);
                    const float v = acc[mt][nt][reg] + bsc;
                    const float* fc = &freqs[((size_t)m * 64 + (d >> 1)) * 2];
                    const float c = fc[0], s = fc[1];
                    const float p = __shfl_xor(v, 1);
                    const float o = (d & 1) ? (v * c + p * s) : (v * c - p * s);
                    const ushort_t hv = bf16_rne(o);
                    const ushort_t lv = bf16_rne(o - bf16_f32(hv));
                    const int hp = __shfl_xor((int)hv, 1);
                    const int lp = __shfl_xor((int)lv, 1);
                    if (!(d & 1)) {
                        const int srow2 = (which == 0) ? m : input_pos[m];
                        *(uint_t*)&oh_b[(size_t)srow2 * HD + d] =
                            (uint_t)hv | ((uint_t)hp << 16);
                        *(uint_t*)&ol_b[(size_t)srow2 * HD + d] =
                            (uint_t)lv | ((uint_t)lp << 16);
                    }
                }
            }
        }
    }
}

// ---------------------------------------------------------------------------
// MFMA flash attention (unchanged from R6/R7 — verified win).
// ---------------------------------------------------------------------------
__global__ __launch_bounds__(256, 2) void attn_mfma_kernel(
    const ushort_t* __restrict__ qhg, const ushort_t* __restrict__ qlg,
    const ushort_t* __restrict__ khg, const ushort_t* __restrict__ klg,
    const ushort_t* __restrict__ vhg, const ushort_t* __restrict__ vlg,
    ushort_t* __restrict__ ctxh, ushort_t* __restrict__ ctxl)
{
    __shared__ ushort_t Khs[2][4096];   // [buf][ks*1024 + key*32 + d8]
    __shared__ ushort_t Kls[2][4096];
    __shared__ ushort_t Vhs[2][4096];   // [buf][dim*32 + key8]
    __shared__ ushort_t Vls[2][4096];
    __shared__ ushort_t Ps[64 * 32];

    const int h = blockIdx.y;
    const int r = (h & 8) ? blockIdx.x : (31 - blockIdx.x);
    const int q0 = r * 64;
    const int ntiles = 2 * r + 2;
    const int t = threadIdx.x;
    const int w = t >> 6, lane = t & 63;
    const int lr = lane & 15, quad = lane >> 4;

    const size_t qrow = (size_t)h * S + q0 + w * 16 + lr;
    bf16x8 qf_h[4], qf_l[4];
    #pragma unroll
    for (int ks = 0; ks < 4; ks++) {
        qf_h[ks] = *(const bf16x8*)&qhg[qrow * HD + ks * 32 + quad * 8];
        qf_l[ks] = *(const bf16x8*)&qlg[qrow * HD + ks * 32 + quad * 8];
    }

    const ushort_t* kh_b = khg + (size_t)h * S * HD;
    const ushort_t* kl_b = klg + (size_t)h * S * HD;
    const ushort_t* vh_b = vhg + (size_t)h * HD * S;
    const ushort_t* vl_b = vlg + (size_t)h * HD * S;

    const int keyq = lane >> 2;   // 0..15
    const int sub  = lane & 3;    // 16B chunk index

    auto stage = [&](int kt, int buf) {
        const int k0 = kt * 32;
        #pragma unroll
        for (int hf = 0; hf < 2; hf++) {
            const size_t ksrc = (size_t)(k0 + hf * 16 + keyq) * HD + w * 32 + sub * 8;
            gload16(kh_b + ksrc, &Khs[buf][w * 1024 + hf * 512]);
            gload16(kl_b + ksrc, &Kls[buf][w * 1024 + hf * 512]);
            const int dim = w * 32 + hf * 16 + keyq;
            const size_t vsrc = (size_t)dim * S + k0 + sub * 8;
            gload16(vh_b + vsrc, &Vhs[buf][(w * 32 + hf * 16) * 32]);
            gload16(vl_b + vsrc, &Vls[buf][(w * 32 + hf * 16) * 32]);
        }
    };

    f32x4 O[8] = {};
    float mrow[4], lrow[4];
    #pragma unroll
    for (int rr = 0; rr < 4; rr++) { mrow[rr] = -1e30f; lrow[rr] = 0.f; }

    const float kSc = 0.08838834764831845f * 1.4426950408889634f; // scale*log2e

    stage(0, 0);

    for (int kt = 0; kt < ntiles; kt++) {
        const int k0 = kt * 32;
        const int cur = kt & 1;
        __syncthreads();  // drains vmcnt -> tile kt visible; buf cur^1 free

        if (kt + 1 < ntiles) stage(kt + 1, cur ^ 1);

        f32x4 sa[2];
        #pragma unroll
        for (int nt = 0; nt < 2; nt++) {
            f32x4 s = {0.f, 0.f, 0.f, 0.f};
            #pragma unroll
            for (int ks = 0; ks < 4; ks++) {
                bf16x8 kf_h = *(const bf16x8*)&Khs[cur][ks * 1024 + (nt * 16 + lr) * 32 + quad * 8];
                bf16x8 kf_l = *(const bf16x8*)&Kls[cur][ks * 1024 + (nt * 16 + lr) * 32 + quad * 8];
                s = __builtin_amdgcn_mfma_f32_16x16x32_bf16(qf_h[ks], kf_h, s, 0, 0, 0);
                s = __builtin_amdgcn_mfma_f32_16x16x32_bf16(qf_l[ks], kf_h, s, 0, 0, 0);
                s = __builtin_amdgcn_mfma_f32_16x16x32_bf16(qf_h[ks], kf_l, s, 0, 0, 0);
            }
            sa[nt] = s;
        }

        const int rowbase = q0 + w * 16 + quad * 4;
        const bool need_mask = (k0 + 31) > (q0 + w * 16);
        float alpha[4], pv0[4], pv1[4];
        #pragma unroll
        for (int rr = 0; rr < 4; rr++) {
            float z0 = sa[0][rr] * kSc;
            float z1 = sa[1][rr] * kSc;
            if (need_mask) {
                const int rowg = rowbase + rr;
                if (k0 + lr > rowg)      z0 = -1e30f;
                if (k0 + 16 + lr > rowg) z1 = -1e30f;
            }
            float rm = fmaxf(z0, z1);
            #pragma unroll
            for (int off = 1; off < 16; off <<= 1)
                rm = fmaxf(rm, __shfl_xor(rm, off));
            const float nm = fmaxf(mrow[rr], rm);
            const float al = exp2f(mrow[rr] - nm);
            const float p0 = exp2f(z0 - nm);
            const float p1 = exp2f(z1 - nm);
            float ts = p0 + p1;
            #pragma unroll
            for (int off = 1; off < 16; off <<= 1)
                ts += __shfl_xor(ts, off);
            lrow[rr] = lrow[rr] * al + ts;
            mrow[rr] = nm;
            alpha[rr] = al;
            pv0[rr] = p0;
            pv1[rr] = p1;
        }

        #pragma unroll
        for (int rr = 0; rr < 4; rr++) {
            const int prow = (w * 16 + quad * 4 + rr) * 32;
            Ps[prow + lr]      = bf16_rne(pv0[rr]);
            Ps[prow + 16 + lr] = bf16_rne(pv1[rr]);
        }
        // no barrier: each wave reads only its own P rows (lgkmcnt orders)

        #pragma unroll
        for (int nt = 0; nt < 8; nt++)
            #pragma unroll
            for (int rr = 0; rr < 4; rr++)
                O[nt][rr] *= alpha[rr];
        const bf16x8 pf = *(const bf16x8*)&Ps[(w * 16 + lr) * 32 + quad * 8];
        #pragma unroll
        for (int nt = 0; nt < 8; nt++) {
            bf16x8 vf_h = *(const bf16x8*)&Vhs[cur][(nt * 16 + lr) * 32 + quad * 8];
            bf16x8 vf_l = *(const bf16x8*)&Vls[cur][(nt * 16 + lr) * 32 + quad * 8];
            O[nt] = __builtin_amdgcn_mfma_f32_16x16x32_bf16(pf, vf_h, O[nt], 0, 0, 0);
            O[nt] = __builtin_amdgcn_mfma_f32_16x16x32_bf16(pf, vf_l, O[nt], 0, 0, 0);
        }
    }

    #pragma unroll
    for (int rr = 0; rr < 4; rr++) {
        const float inv = 1.0f / lrow[rr];
        const int qg = q0 + w * 16 + quad * 4 + rr;
        const size_t roff = (size_t)qg * D + h * HD;
        #pragma unroll
        for (int nt = 0; nt < 8; nt++) {
            const float o = O[nt][rr] * inv;
            const ushort_t hv = bf16_rne(o);
            const ushort_t lv = bf16_rne(o - bf16_f32(hv));
            const int hp = __shfl_xor((int)hv, 1);
            const int lp = __shfl_xor((int)lv, 1);
            if (!(lr & 1)) {
                *(uint_t*)&ctxh[roff + nt * 16 + lr] = (uint_t)hv | ((uint_t)hp << 16);
                *(uint_t*)&ctxl[roff + nt * 16 + lr] = (uint_t)lv | ((uint_t)lp << 16);
            }
        }
    }
}

// ---------------------------------------------------------------------------
// Dense GEMM (MFMA, R8 core): out = ctx @ Wdense + b, 32x32 C-layout.
// ---------------------------------------------------------------------------
__global__ __launch_bounds__(256, 4) void gemm_dense_mfma(
    const ushort_t* __restrict__ Ah, const ushort_t* __restrict__ Al,
    const ushort_t* __restrict__ Wth, const ushort_t* __restrict__ Wtl,
    const float* __restrict__ bias, float* __restrict__ out)
{
    __shared__ ushort_t lds[2 * BUF_ELEMS];   // 32 KB
    const int t = threadIdx.x;
    const int col0 = blockIdx.x * 128;
    const int row0 = blockIdx.y * 128;

    f32x16 acc[2][2] = {};
    mm_core_split(Ah + (size_t)row0 * D, Al + (size_t)row0 * D,
                  Wth + (size_t)col0 * D, Wtl + (size_t)col0 * D,
                  D, lds, t, acc);

    const int lane = t & 63;
    const int col  = lane & 31;
    const int half = lane >> 5;
    const int wm = ((t >> 6) & 1) * 64;
    const int wn = ((t >> 6) >> 1) * 64;

    #pragma unroll
    for (int nt = 0; nt < 2; nt++) {
        const int n = col0 + wn + nt * 32 + col;
        const float bsc = bias[n];
        #pragma unroll
        for (int mt = 0; mt < 2; mt++) {
            #pragma unroll
            for (int reg = 0; reg < 16; reg++) {
                const int m = row0 + wm + mt * 32 +
                              (reg & 3) + 4 * half + 8 * (reg >> 2);
                const float o = acc[mt][nt][reg] + bsc;
                const float po = __shfl_xor(o, 1);
                if (!(n & 1))
                    *(float2*)&out[(size_t)m * D + n] = make_float2(o, po);
            }
        }
    }
}

// ---------------------------------------------------------------------------
// Fallback f32 path (R2, known-good) for small workspace.
// ---------------------------------------------------------------------------
__global__ __launch_bounds__(256) void gemm_qkv_kernel(
    const float* __restrict__ x, const float* __restrict__ W,
    const float* __restrict__ bias, const float* __restrict__ freqs,
    const int* __restrict__ input_pos,
    float* __restrict__ qb, float* __restrict__ kb, float* __restrict__ vb)
{
    __shared__ float As[16][68];
    __shared__ float Bs[16][64];
    const int bx = blockIdx.x;
    const int by = blockIdx.y;
    const int tid = threadIdx.x;
    const int tx = tid & 15, ty = tid >> 4;
    const int row0 = by * 64, col0 = bx * 64;
    const int am = tid >> 2;
    const int ak = (tid & 3) * 4;
    const int bk = tid >> 4;
    const int bn = (tid & 15) * 4;
    float acc[4][4] = {};
    for (int k0 = 0; k0 < D; k0 += 16) {
        float4 av = *(const float4*)&x[(size_t)(row0 + am) * D + k0 + ak];
        float4 bv = *(const float4*)&W[(size_t)(k0 + bk) * N3 + col0 + bn];
        __syncthreads();
        As[ak + 0][am] = av.x; As[ak + 1][am] = av.y;
        As[ak + 2][am] = av.z; As[ak + 3][am] = av.w;
        *(float4*)&Bs[bk][bn] = bv;
        __syncthreads();
        #pragma unroll
        for (int k = 0; k < 16; k++) {
            float4 a4 = *(const float4*)&As[k][ty * 4];
            float4 b4 = *(const float4*)&Bs[k][tx * 4];
            float a[4] = {a4.x, a4.y, a4.z, a4.w};
            float b[4] = {b4.x, b4.y, b4.z, b4.w};
            #pragma unroll
            for (int r = 0; r < 4; r++)
                #pragma unroll
                for (int c = 0; c < 4; c++)
                    acc[r][c] += a[r] * b[c];
        }
    }
    const int j0 = col0 + tx * 4;
    const int which = j0 >> 11;
    const int hh = (j0 & 2047) >> 7;
    const int d0 = j0 & 127;
    const float bv0 = bias[j0 + 0], bv1 = bias[j0 + 1];
    const float bv2 = bias[j0 + 2], bv3 = bias[j0 + 3];
    #pragma unroll
    for (int r = 0; r < 4; r++) {
        const int grow = row0 + ty * 4 + r;
        float v0 = acc[r][0] + bv0, v1 = acc[r][1] + bv1;
        float v2 = acc[r][2] + bv2, v3 = acc[r][3] + bv3;
        if (which == 2) {
            const int pos = input_pos[grow];
            float4 o4 = make_float4(v0, v1, v2, v3);
            *(float4*)&vb[((size_t)hh * S + pos) * HD + d0] = o4;
        } else {
            const float* fc = &freqs[((size_t)grow * 64 + (d0 >> 1)) * 2];
            float c0 = fc[0], s0 = fc[1], c1 = fc[2], s1 = fc[3];
            float o0 = v0 * c0 - v1 * s0, o1 = v1 * c0 + v0 * s0;
            float o2 = v2 * c1 - v3 * s1, o3 = v3 * c1 + v2 * s1;
            float4 o4 = make_float4(o0, o1, o2, o3);
            if (which == 0) {
                *(float4*)&qb[((size_t)hh * S + grow) * HD + d0] = o4;
            } else {
                const int pos = input_pos[grow];
                *(float4*)&kb[((size_t)hh * S + pos) * HD + d0] = o4;
            }
        }
    }
}

#define BQ 64
#define ABK 32
#define QSTR 132
#define KVSTR 132
#define PSTR 68

__global__ __launch_bounds__(256) void attn_kernel(
    const float* __restrict__ qb, const float* __restrict__ kb,
    const float* __restrict__ vb, float* __restrict__ ctx)
{
    __shared__ float Qs[BQ * QSTR];
    __shared__ float KV[ABK * KVSTR];
    __shared__ float Psf[ABK * PSTR];

    const int pa = blockIdx.x;
    const int h  = blockIdx.y;
    const int t  = threadIdx.x;
    const int ty = t >> 4, tx = t & 15;
    const int i0  = ty * 4;
    const int j0  = tx * 2;
    const int dd0 = tx * 8;
    const int lr = t >> 3;
    const int lc = (t & 7) * 4;

    const float* kbase = kb + (size_t)h * S * HD;
    const float* vbase = vb + (size_t)h * S * HD;
    const float kSc = 0.08838834764831845f * 1.4426950408889634f;

    for (int ph = 0; ph < 2; ph++) {
        const int r = (ph == 0) ? pa : 31 - pa;
        const int q0 = r * BQ;
        const int ntiles = 2 * r + 2;

        #pragma unroll
        for (int pp = 0; pp < 2; pp++) {
            const int iq = lr + pp * 32;
            const float* src = qb + ((size_t)h * S + q0 + iq) * HD;
            #pragma unroll
            for (int ch = 0; ch < 4; ch++)
                *(float4*)&Qs[iq * QSTR + lc + ch * 32] =
                    *(const float4*)&src[lc + ch * 32];
        }

        float O[4][8] = {};
        float m[4], l[4];
        #pragma unroll
        for (int rr = 0; rr < 4; rr++) { m[rr] = -1e30f; l[rr] = 0.f; }

        float4 kpref[4];
        #pragma unroll
        for (int ch = 0; ch < 4; ch++)
            kpref[ch] = *(const float4*)&kbase[(size_t)lr * HD + lc + ch * 32];

        __syncthreads();

        for (int kt = 0; kt < ntiles; kt++) {
            const int k0 = kt * ABK;

            #pragma unroll
            for (int ch = 0; ch < 4; ch++)
                *(float4*)&KV[lr * KVSTR + lc + ch * 32] = kpref[ch];
            __syncthreads();

            float4 vpref[4];
            #pragma unroll
            for (int ch = 0; ch < 4; ch++)
                vpref[ch] = *(const float4*)&vbase[(size_t)(k0 + lr) * HD + lc + ch * 32];

            float acc[4][2] = {};
            #pragma unroll 4
            for (int d0 = 0; d0 < HD; d0 += 4) {
                float4 ka = *(const float4*)&KV[(j0 + 0) * KVSTR + d0];
                float4 kb4 = *(const float4*)&KV[(j0 + 1) * KVSTR + d0];
                #pragma unroll
                for (int rr = 0; rr < 4; rr++) {
                    float4 q4 = *(const float4*)&Qs[(i0 + rr) * QSTR + d0];
                    acc[rr][0] += q4.x * ka.x + q4.y * ka.y + q4.z * ka.z + q4.w * ka.w;
                    acc[rr][1] += q4.x * kb4.x + q4.y * kb4.y + q4.z * kb4.z + q4.w * kb4.w;
                }
            }

            const bool need_mask = (k0 + ABK - 1) > q0;
            float p[4][2], alpha[4];
            #pragma unroll
            for (int rr = 0; rr < 4; rr++) {
                float z0 = acc[rr][0] * kSc;
                float z1 = acc[rr][1] * kSc;
                if (need_mask) {
                    if (k0 + j0 + 0 > q0 + i0 + rr) z0 = -1e30f;
                    if (k0 + j0 + 1 > q0 + i0 + rr) z1 = -1e30f;
                }
                float rmax = fmaxf(z0, z1);
                #pragma unroll
                for (int off = 1; off < 16; off <<= 1)
                    rmax = fmaxf(rmax, __shfl_xor(rmax, off, 16));
                const float nm = fmaxf(m[rr], rmax);
                alpha[rr] = exp2f(m[rr] - nm);
                p[rr][0] = exp2f(z0 - nm);
                p[rr][1] = exp2f(z1 - nm);
                float ts = p[rr][0] + p[rr][1];
                #pragma unroll
                for (int off = 1; off < 16; off <<= 1)
                    ts += __shfl_xor(ts, off, 16);
                l[rr] = l[rr] * alpha[rr] + ts;
                m[rr] = nm;
            }
            __syncthreads();

            #pragma unroll
            for (int ch = 0; ch < 4; ch++)
                *(float4*)&KV[lr * KVSTR + lc + ch * 32] = vpref[ch];
            *(float4*)&Psf[(j0 + 0) * PSTR + i0] =
                make_float4(p[0][0], p[1][0], p[2][0], p[3][0]);
            *(float4*)&Psf[(j0 + 1) * PSTR + i0] =
                make_float4(p[0][1], p[1][1], p[2][1], p[3][1]);
            if (kt + 1 < ntiles) {
                #pragma unroll
                for (int ch = 0; ch < 4; ch++)
                    kpref[ch] = *(const float4*)&kbase[(size_t)(k0 + ABK + lr) * HD + lc + ch * 32];
            }
            __syncthreads();

            #pragma unroll
            for (int rr = 0; rr < 4; rr++)
                #pragma unroll
                for (int c = 0; c < 8; c++)
                    O[rr][c] *= alpha[rr];
            #pragma unroll 4
            for (int j = 0; j < ABK; j++) {
                float4 pj = *(const float4*)&Psf[j * PSTR + i0];
                float4 v0 = *(const float4*)&KV[j * KVSTR + dd0];
                float4 v1 = *(const float4*)&KV[j * KVSTR + dd0 + 4];
                const float pr[4] = {pj.x, pj.y, pj.z, pj.w};
                const float vv[8] = {v0.x, v0.y, v0.z, v0.w, v1.x, v1.y, v1.z, v1.w};
                #pragma unroll
                for (int rr = 0; rr < 4; rr++)
                    #pragma unroll
                    for (int c = 0; c < 8; c++)
                        O[rr][c] += pr[rr] * vv[c];
            }
            __syncthreads();
        }

        #pragma unroll
        for (int rr = 0; rr < 4; rr++) {
            const float inv = 1.0f / l[rr];
            const int qg = q0 + i0 + rr;
            float4 o0 = make_float4(O[rr][0] * inv, O[rr][1] * inv,
                                    O[rr][2] * inv, O[rr][3] * inv);
            float4 o1 = make_float4(O[rr][4] * inv, O[rr][5] * inv,
                                    O[rr][6] * inv, O[rr][7] * inv);
            float* dst = &ctx[((size_t)qg * H + h) * HD + dd0];
            *(float4*)&dst[0] = o0;
            *(float4*)&dst[4] = o1;
        }
        __syncthreads();
    }
}

__global__ __launch_bounds__(256) void gemm_dense_kernel(
    const float* __restrict__ A, const float* __restrict__ W,
    const float* __restrict__ bias, float* __restrict__ out)
{
    __shared__ float As[16][68];
    __shared__ float Bs[16][64];
    const int bx = blockIdx.x;
    const int by = blockIdx.y;
    const int tid = threadIdx.x;
    const int tx = tid & 15, ty = tid >> 4;
    const int row0 = by * 64, col0 = bx * 64;
    const int am = tid >> 2;
    const int ak = (tid & 3) * 4;
    const int bk = tid >> 4;
    const int bn = (tid & 15) * 4;
    float acc[4][4] = {};
    for (int k0 = 0; k0 < D; k0 += 16) {
        float4 av = *(const float4*)&A[(size_t)(row0 + am) * D + k0 + ak];
        float4 bv = *(const float4*)&W[(size_t)(k0 + bk) * D + col0 + bn];
        __syncthreads();
        As[ak + 0][am] = av.x; As[ak + 1][am] = av.y;
        As[ak + 2][am] = av.z; As[ak + 3][am] = av.w;
        *(float4*)&Bs[bk][bn] = bv;
        __syncthreads();
        #pragma unroll
        for (int k = 0; k < 16; k++) {
            float4 a4 = *(const float4*)&As[k][ty * 4];
            float4 b4 = *(const float4*)&Bs[k][tx * 4];
            float a[4] = {a4.x, a4.y, a4.z, a4.w};
            float b[4] = {b4.x, b4.y, b4.z, b4.w};
            #pragma unroll
            for (int r = 0; r < 4; r++)
                #pragma unroll
                for (int c = 0; c < 4; c++)
                    acc[r][c] += a[r] * b[c];
        }
    }
    const int j0 = col0 + tx * 4;
    const float bv0 = bias[j0 + 0], bv1 = bias[j0 + 1];
    const float bv2 = bias[j0 + 2], bv3 = bias[j0 + 3];
    #pragma unroll
    for (int r = 0; r < 4; r++) {
        const int grow = row0 + ty * 4 + r;
        float4 o4 = make_float4(acc[r][0] + bv0, acc[r][1] + bv1,
                                acc[r][2] + bv2, acc[r][3] + bv3);
        *(float4*)&out[(size_t)grow * D + j0] = o4;
    }
}

extern "C" void kernel_launch(void* const* d_in, const int* in_sizes, int n_in,
                              void* d_out, int out_size, void* d_ws, size_t ws_size,
                              hipStream_t stream) {
    const float* x      = (const float*)d_in[0];
    const float* freqs  = (const float*)d_in[1];
    const int*   pos    = (const int*)d_in[2];
    const float* Wqkv   = (const float*)d_in[3];
    const float* bqkv   = (const float*)d_in[4];
    const float* Wdense = (const float*)d_in[5];
    const float* bdense = (const float*)d_in[6];
    float* out = (float*)d_out;

    const size_t nSD = (size_t)S * D;   // 4 Mi elems
    const size_t nW1 = (size_t)D * N3;  // 12 Mi elems

    // mfma path ws (all bf16): 12 nSD-sized arrays + 2 nW1-sized = 144 MiB
    const size_t needed = (12 * nSD + 2 * nW1) * sizeof(ushort_t);

    if (ws_size >= needed) {
        ushort_t* qh   = (ushort_t*)d_ws;
        ushort_t* ql   = qh + nSD;
        ushort_t* kh   = ql + nSD;
        ushort_t* kl   = kh + nSD;
        ushort_t* vh   = kl + nSD;
        ushort_t* vl   = vh + nSD;
        ushort_t* ctxh = vl + nSD;
        ushort_t* ctxl = ctxh + nSD;
        ushort_t* xh   = ctxl + nSD;
        ushort_t* xl   = xh + nSD;
        ushort_t* Wth  = xl + nSD;
        ushort_t* Wtl  = Wth + nW1;
        ushort_t* Wdth = Wtl + nW1;
        ushort_t* Wdtl = Wdth + nSD;

        convert_split_kernel<<<nSD / 4 / 256, 256, 0, stream>>>(x, xh, xl);
        dim3 gt1(D / 32, N3 / 32);
        convert_split_t_kernel<<<gt1, 256, 0, stream>>>(Wqkv, Wth, Wtl, D, N3);
        dim3 gt2(D / 32, D / 32);
        convert_split_t_kernel<<<gt2, 256, 0, stream>>>(Wdense, Wdth, Wdtl, D, D);

        dim3 g1(N3 / 128, S / 128);
        gemm_qkv_mfma<<<g1, 256, 0, stream>>>(xh, xl, Wth, Wtl, bqkv, freqs,
                                              pos, qh, ql, kh, kl, vh, vl);
        dim3 g2(32, H);
        attn_mfma_kernel<<<g2, 256, 0, stream>>>(qh, ql, kh, kl, vh, vl,
                                                 ctxh, ctxl);
        dim3 g3(D / 128, S / 128);
        gemm_dense_mfma<<<g3, 256, 0, stream>>>(ctxh, ctxl, Wdth, Wdtl, bdense, out);
    } else {
        // fallback: R2 f32 path (needs only 64 MiB)
        float* qb  = (float*)d_ws;
        float* kb  = qb + (size_t)H * S * HD;
        float* vb  = kb + (size_t)H * S * HD;
        float* ctx = vb + (size_t)H * S * HD;
        dim3 g1(N3 / 64, S / 64);
        gemm_qkv_kernel<<<g1, 256, 0, stream>>>(x, Wqkv, bqkv, freqs, pos, qb, kb, vb);
        dim3 g2(16, H);
        attn_kernel<<<g2, 256, 0, stream>>>(qb, kb, vb, ctx);
        dim3 g3(D / 64, S / 64);
        gemm_dense_kernel<<<g3, 256, 0, stream>>>(ctx, Wdense, bdense, out);
    }
}

// Round 9
// 541.379 us; speedup vs baseline: 1.1807x; 1.1807x over previous
//
#include <hip/hip_runtime.h>

#define S 2048
#define D 2048
#define H 16
#define HD 128
#define N3 6144  // 3*D

typedef __attribute__((ext_vector_type(8))) short bf16x8;
typedef __attribute__((ext_vector_type(4))) float f32x4;
typedef unsigned short ushort_t;
typedef unsigned int uint_t;

// ---------------------------------------------------------------------------
// bf16 split helpers (round-to-nearest-even)
// ---------------------------------------------------------------------------
__device__ __forceinline__ ushort_t bf16_rne(float f) {
    uint_t u = __float_as_uint(f);
    u += 0x7fffu + ((u >> 16) & 1u);
    return (ushort_t)(u >> 16);
}
__device__ __forceinline__ float bf16_f32(ushort_t h) {
    return __uint_as_float(((uint_t)h) << 16);
}

// split f32 row-major -> hi/lo bf16 row-major (same layout)
__global__ __launch_bounds__(256) void convert_split_kernel(
    const float* __restrict__ in, ushort_t* __restrict__ hi,
    ushort_t* __restrict__ lo)
{
    const int i = blockIdx.x * 256 + threadIdx.x;  // per float4
    float4 v = ((const float4*)in)[i];
    ushort_t h0 = bf16_rne(v.x), h1 = bf16_rne(v.y);
    ushort_t h2 = bf16_rne(v.z), h3 = bf16_rne(v.w);
    ushort4 hv = make_ushort4(h0, h1, h2, h3);
    ushort4 lv = make_ushort4(bf16_rne(v.x - bf16_f32(h0)),
                              bf16_rne(v.y - bf16_f32(h1)),
                              bf16_rne(v.z - bf16_f32(h2)),
                              bf16_rne(v.w - bf16_f32(h3)));
    ((ushort4*)hi)[i] = hv;
    ((ushort4*)lo)[i] = lv;
}

// W [K][N] f32 -> Wt hi/lo [N][K] bf16 (transpose + split), 32x32 tiles.
__global__ __launch_bounds__(256) void convert_split_t_kernel(
    const float* __restrict__ in, ushort_t* __restrict__ hi,
    ushort_t* __restrict__ lo, int Kdim, int Ndim)
{
    __shared__ float tile[32][33];
    const int k0 = blockIdx.x * 32, n0 = blockIdx.y * 32;
    const int tx = threadIdx.x & 31, ty = threadIdx.x >> 5;  // ty 0..7
    #pragma unroll
    for (int r = 0; r < 4; r++)
        tile[ty + r * 8][tx] = in[(size_t)(k0 + ty + r * 8) * Ndim + n0 + tx];
    __syncthreads();
    const int n  = threadIdx.x >> 3;        // 0..31 local col
    const int kc = (threadIdx.x & 7) * 4;   // 0..28 local k chunk
    const float v0 = tile[kc + 0][n], v1 = tile[kc + 1][n];
    const float v2 = tile[kc + 2][n], v3 = tile[kc + 3][n];
    const ushort_t h0 = bf16_rne(v0), h1 = bf16_rne(v1);
    const ushort_t h2 = bf16_rne(v2), h3 = bf16_rne(v3);
    const size_t off = (size_t)(n0 + n) * Kdim + k0 + kc;
    *(ushort4*)&hi[off] = make_ushort4(h0, h1, h2, h3);
    *(ushort4*)&lo[off] = make_ushort4(bf16_rne(v0 - bf16_f32(h0)),
                                       bf16_rne(v1 - bf16_f32(h1)),
                                       bf16_rne(v2 - bf16_f32(h2)),
                                       bf16_rne(v3 - bf16_f32(h3)));
}

// ---------------------------------------------------------------------------
// async global->LDS, 16 B per lane, wave-uniform LDS base (HW adds lane*16).
// ---------------------------------------------------------------------------
__device__ __forceinline__ void gload16(const ushort_t* g, ushort_t* l) {
    __builtin_amdgcn_global_load_lds(
        (const __attribute__((address_space(1))) unsigned int*)g,
        (__attribute__((address_space(3))) unsigned int*)l, 16, 0, 0);
}

// ---------------------------------------------------------------------------
// Split-bf16 MFMA GEMM core — REVERTED to R7 (verified 211 us qkv):
// BK=32, 16x16x32, double-buffered 64 KB LDS, m97 bank-benign 64 B rows.
// R8's BK=16/32x32 interleaved variant REGRESSED (3x bank conflicts: all
// lanes' b128 starts on banks {0,4,16,20}; + 32 B strided DRAM over-fetch).
// Do not re-try interleaved rows.
// ---------------------------------------------------------------------------
#define BK 32
#define TILE_ELEMS (128 * BK)

__device__ __forceinline__ void mm_core_split(
    const ushort_t* __restrict__ Agh, const ushort_t* __restrict__ Agl,
    const ushort_t* __restrict__ Bgh, const ushort_t* __restrict__ Bgl,
    const int K, ushort_t* lds, const int t, f32x4 (&acc)[4][4])
{
    const int lane = t & 63;
    const int wv   = t >> 6;
    const int lrow = lane >> 2;
    const int lk   = (lane & 3) * 8;
    const int quad = lane >> 4;
    const int lr   = lane & 15;
    const int wm   = (wv & 1) * 64;
    const int wn   = (wv >> 1) * 64;

    const int r0  = wv * 16;
    const int lo0 = r0 * BK;
    const int lo1 = (r0 + 64) * BK;

    auto stage = [&](int k0, int buf) {
        ushort_t* base = lds + buf * 4 * TILE_ELEMS;
        ushort_t* As_h = base;
        ushort_t* As_l = base + TILE_ELEMS;
        ushort_t* Bs_h = base + 2 * TILE_ELEMS;
        ushort_t* Bs_l = base + 3 * TILE_ELEMS;
        const size_t go0 = (size_t)(r0 + lrow) * K + k0 + lk;
        const size_t go1 = (size_t)(r0 + 64 + lrow) * K + k0 + lk;
        gload16(Agh + go0, As_h + lo0);
        gload16(Agh + go1, As_h + lo1);
        gload16(Agl + go0, As_l + lo0);
        gload16(Agl + go1, As_l + lo1);
        gload16(Bgh + go0, Bs_h + lo0);
        gload16(Bgh + go1, Bs_h + lo1);
        gload16(Bgl + go0, Bs_l + lo0);
        gload16(Bgl + go1, Bs_l + lo1);
    };

    stage(0, 0);

    const int niter = K / BK;
    for (int it = 0; it < niter; it++) {
        const int cur = it & 1;
        __syncthreads();  // drains vmcnt: tile it visible; buf cur^1 free

        if (it + 1 < niter) stage((it + 1) * BK, cur ^ 1);

        ushort_t* base = lds + cur * 4 * TILE_ELEMS;
        ushort_t* As_h = base;
        ushort_t* As_l = base + TILE_ELEMS;
        ushort_t* Bs_h = base + 2 * TILE_ELEMS;
        ushort_t* Bs_l = base + 3 * TILE_ELEMS;

        bf16x8 af_h[4], af_l[4], bf_h[4], bf_l[4];
        #pragma unroll
        for (int i = 0; i < 4; i++) {
            af_h[i] = *(const bf16x8*)&As_h[(wm + i * 16 + lr) * BK + quad * 8];
            af_l[i] = *(const bf16x8*)&As_l[(wm + i * 16 + lr) * BK + quad * 8];
            bf_h[i] = *(const bf16x8*)&Bs_h[(wn + i * 16 + lr) * BK + quad * 8];
            bf_l[i] = *(const bf16x8*)&Bs_l[(wn + i * 16 + lr) * BK + quad * 8];
        }
        #pragma unroll
        for (int mt = 0; mt < 4; mt++)
            #pragma unroll
            for (int nt = 0; nt < 4; nt++) {
                acc[mt][nt] = __builtin_amdgcn_mfma_f32_16x16x32_bf16(
                    af_h[mt], bf_h[nt], acc[mt][nt], 0, 0, 0);
                acc[mt][nt] = __builtin_amdgcn_mfma_f32_16x16x32_bf16(
                    af_h[mt], bf_l[nt], acc[mt][nt], 0, 0, 0);
                acc[mt][nt] = __builtin_amdgcn_mfma_f32_16x16x32_bf16(
                    af_l[mt], bf_h[nt], acc[mt][nt], 0, 0, 0);
            }
    }
}

// ---------------------------------------------------------------------------
// QKV GEMM (MFMA) with split-bf16 outputs (R7 epilogue).
// ---------------------------------------------------------------------------
__global__ __launch_bounds__(256) void gemm_qkv_mfma(
    const ushort_t* __restrict__ xh, const ushort_t* __restrict__ xl,
    const ushort_t* __restrict__ Wth, const ushort_t* __restrict__ Wtl,
    const float* __restrict__ bias, const float* __restrict__ freqs,
    const int* __restrict__ input_pos,
    ushort_t* __restrict__ qhg, ushort_t* __restrict__ qlg,
    ushort_t* __restrict__ khg, ushort_t* __restrict__ klg,
    ushort_t* __restrict__ vhg, ushort_t* __restrict__ vlg)
{
    __shared__ ushort_t lds[2 * 4 * TILE_ELEMS];   // 64 KB
    const int t = threadIdx.x;
    const int col0 = blockIdx.x * 128;
    const int row0 = blockIdx.y * 128;

    f32x4 acc[4][4] = {};
    mm_core_split(xh + (size_t)row0 * D, xl + (size_t)row0 * D,
                  Wth + (size_t)col0 * D, Wtl + (size_t)col0 * D,
                  D, lds, t, acc);

    const int lane = t & 63;
    const int quad = lane >> 4;
    const int lr   = lane & 15;
    const int wm = ((t >> 6) & 1) * 64;
    const int wn = ((t >> 6) >> 1) * 64;

    const int which = col0 >> 11;           // 0=q 1=k 2=v
    const int hh = (col0 & 2047) >> 7;

    if (which == 2) {
        ushort_t* vh_b = vhg + (size_t)hh * HD * S;
        ushort_t* vl_b = vlg + (size_t)hh * HD * S;
        #pragma unroll
        for (int nt = 0; nt < 4; nt++) {
            const int d = wn + nt * 16 + lr;
            const float bsc = bias[col0 + d];
            #pragma unroll
            for (int mt = 0; mt < 4; mt++) {
                #pragma unroll
                for (int reg = 0; reg < 4; reg++) {
                    const int m = row0 + wm + mt * 16 + quad * 4 + reg;
                    const float v = acc[mt][nt][reg] + bsc;
                    const ushort_t hv = bf16_rne(v);
                    const ushort_t lv = bf16_rne(v - bf16_f32(hv));
                    const int pos = input_pos[m];
                    vh_b[(size_t)d * S + pos] = hv;
                    vl_b[(size_t)d * S + pos] = lv;
                }
            }
        }
    } else {
        ushort_t* oh_b = ((which == 0) ? qhg : khg) + (size_t)hh * S * HD;
        ushort_t* ol_b = ((which == 0) ? qlg : klg) + (size_t)hh * S * HD;
        #pragma unroll
        for (int nt = 0; nt < 4; nt++) {
            const int d = wn + nt * 16 + lr;
            const float bsc = bias[col0 + d];
            #pragma unroll
            for (int mt = 0; mt < 4; mt++) {
                #pragma unroll
                for (int reg = 0; reg < 4; reg++) {
                    const int m = row0 + wm + mt * 16 + quad * 4 + reg;
                    const float v = acc[mt][nt][reg] + bsc;
                    const float* fc = &freqs[((size_t)m * 64 + (d >> 1)) * 2];
                    const float c = fc[0], s = fc[1];
                    const float p = __shfl_xor(v, 1);
                    const float o = (d & 1) ? (v * c + p * s) : (v * c - p * s);
                    const ushort_t hv = bf16_rne(o);
                    const ushort_t lv = bf16_rne(o - bf16_f32(hv));
                    const int hp = __shfl_xor((int)hv, 1);
                    const int lp = __shfl_xor((int)lv, 1);
                    if (!(d & 1)) {
                        const int srow = (which == 0) ? m : input_pos[m];
                        *(uint_t*)&oh_b[(size_t)srow * HD + d] =
                            (uint_t)hv | ((uint_t)hp << 16);
                        *(uint_t*)&ol_b[(size_t)srow * HD + d] =
                            (uint_t)lv | ((uint_t)lp << 16);
                    }
                }
            }
        }
    }
}

// ---------------------------------------------------------------------------
// MFMA flash attention, R9: R6/R7 structure + ones-column l. The running
// softmax denominator is accumulated by one extra PV MFMA against a ones
// B-fragment (linear reduction -> matrix pipe), removing the 16-shuffle
// sum-reduce per tile. Max-reduce (nonlinear) keeps the shuffle chain.
// ---------------------------------------------------------------------------
__global__ __launch_bounds__(256, 2) void attn_mfma_kernel(
    const ushort_t* __restrict__ qhg, const ushort_t* __restrict__ qlg,
    const ushort_t* __restrict__ khg, const ushort_t* __restrict__ klg,
    const ushort_t* __restrict__ vhg, const ushort_t* __restrict__ vlg,
    ushort_t* __restrict__ ctxh, ushort_t* __restrict__ ctxl)
{
    __shared__ ushort_t Khs[2][4096];   // [buf][ks*1024 + key*32 + d8]
    __shared__ ushort_t Kls[2][4096];
    __shared__ ushort_t Vhs[2][4096];   // [buf][dim*32 + key8]
    __shared__ ushort_t Vls[2][4096];
    __shared__ ushort_t Ps[64 * 32];

    const int h = blockIdx.y;
    const int r = (h & 8) ? blockIdx.x : (31 - blockIdx.x);
    const int q0 = r * 64;
    const int ntiles = 2 * r + 2;
    const int t = threadIdx.x;
    const int w = t >> 6, lane = t & 63;
    const int lr = lane & 15, quad = lane >> 4;

    const size_t qrow = (size_t)h * S + q0 + w * 16 + lr;
    bf16x8 qf_h[4], qf_l[4];
    #pragma unroll
    for (int ks = 0; ks < 4; ks++) {
        qf_h[ks] = *(const bf16x8*)&qhg[qrow * HD + ks * 32 + quad * 8];
        qf_l[ks] = *(const bf16x8*)&qlg[qrow * HD + ks * 32 + quad * 8];
    }

    const ushort_t* kh_b = khg + (size_t)h * S * HD;
    const ushort_t* kl_b = klg + (size_t)h * S * HD;
    const ushort_t* vh_b = vhg + (size_t)h * HD * S;
    const ushort_t* vl_b = vlg + (size_t)h * HD * S;

    const int keyq = lane >> 2;   // 0..15
    const int sub  = lane & 3;    // 16B chunk index

    auto stage = [&](int kt, int buf) {
        const int k0 = kt * 32;
        #pragma unroll
        for (int hf = 0; hf < 2; hf++) {
            const size_t ksrc = (size_t)(k0 + hf * 16 + keyq) * HD + w * 32 + sub * 8;
            gload16(kh_b + ksrc, &Khs[buf][w * 1024 + hf * 512]);
            gload16(kl_b + ksrc, &Kls[buf][w * 1024 + hf * 512]);
            const int dim = w * 32 + hf * 16 + keyq;
            const size_t vsrc = (size_t)dim * S + k0 + sub * 8;
            gload16(vh_b + vsrc, &Vhs[buf][(w * 32 + hf * 16) * 32]);
            gload16(vl_b + vsrc, &Vls[buf][(w * 32 + hf * 16) * 32]);
        }
    };

    f32x4 O[8] = {};
    f32x4 Ol = {0.f, 0.f, 0.f, 0.f};   // ones-column: per-row softmax denom
    float mrow[4];
    #pragma unroll
    for (int rr = 0; rr < 4; rr++) mrow[rr] = -1e30f;

    // bf16 1.0 in every element
    bf16x8 onesv;
    #pragma unroll
    for (int i = 0; i < 8; i++) onesv[i] = (short)0x3F80;

    const float kSc = 0.08838834764831845f * 1.4426950408889634f; // scale*log2e

    stage(0, 0);

    for (int kt = 0; kt < ntiles; kt++) {
        const int k0 = kt * 32;
        const int cur = kt & 1;
        __syncthreads();  // drains vmcnt -> tile kt visible; buf cur^1 free

        if (kt + 1 < ntiles) stage(kt + 1, cur ^ 1);

        f32x4 sa[2];
        #pragma unroll
        for (int nt = 0; nt < 2; nt++) {
            f32x4 s = {0.f, 0.f, 0.f, 0.f};
            #pragma unroll
            for (int ks = 0; ks < 4; ks++) {
                bf16x8 kf_h = *(const bf16x8*)&Khs[cur][ks * 1024 + (nt * 16 + lr) * 32 + quad * 8];
                bf16x8 kf_l = *(const bf16x8*)&Kls[cur][ks * 1024 + (nt * 16 + lr) * 32 + quad * 8];
                s = __builtin_amdgcn_mfma_f32_16x16x32_bf16(qf_h[ks], kf_h, s, 0, 0, 0);
                s = __builtin_amdgcn_mfma_f32_16x16x32_bf16(qf_l[ks], kf_h, s, 0, 0, 0);
                s = __builtin_amdgcn_mfma_f32_16x16x32_bf16(qf_h[ks], kf_l, s, 0, 0, 0);
            }
            sa[nt] = s;
        }

        const int rowbase = q0 + w * 16 + quad * 4;
        const bool need_mask = (k0 + 31) > (q0 + w * 16);
        float alpha[4], pv0[4], pv1[4];
        #pragma unroll
        for (int rr = 0; rr < 4; rr++) {
            float z0 = sa[0][rr] * kSc;
            float z1 = sa[1][rr] * kSc;
            if (need_mask) {
                const int rowg = rowbase + rr;
                if (k0 + lr > rowg)      z0 = -1e30f;
                if (k0 + 16 + lr > rowg) z1 = -1e30f;
            }
            float rm = fmaxf(z0, z1);
            #pragma unroll
            for (int off = 1; off < 16; off <<= 1)
                rm = fmaxf(rm, __shfl_xor(rm, off));
            const float nm = fmaxf(mrow[rr], rm);
            alpha[rr] = exp2f(mrow[rr] - nm);
            pv0[rr] = exp2f(z0 - nm);
            pv1[rr] = exp2f(z1 - nm);
            mrow[rr] = nm;
        }

        #pragma unroll
        for (int rr = 0; rr < 4; rr++) {
            const int prow = (w * 16 + quad * 4 + rr) * 32;
            Ps[prow + lr]      = bf16_rne(pv0[rr]);
            Ps[prow + 16 + lr] = bf16_rne(pv1[rr]);
        }
        // no barrier: each wave reads only its own P rows (lgkmcnt orders)

        #pragma unroll
        for (int nt = 0; nt < 8; nt++)
            #pragma unroll
            for (int rr = 0; rr < 4; rr++)
                O[nt][rr] *= alpha[rr];
        #pragma unroll
        for (int rr = 0; rr < 4; rr++)
            Ol[rr] *= alpha[rr];
        const bf16x8 pf = *(const bf16x8*)&Ps[(w * 16 + lr) * 32 + quad * 8];
        #pragma unroll
        for (int nt = 0; nt < 8; nt++) {
            bf16x8 vf_h = *(const bf16x8*)&Vhs[cur][(nt * 16 + lr) * 32 + quad * 8];
            bf16x8 vf_l = *(const bf16x8*)&Vls[cur][(nt * 16 + lr) * 32 + quad * 8];
            O[nt] = __builtin_amdgcn_mfma_f32_16x16x32_bf16(pf, vf_h, O[nt], 0, 0, 0);
            O[nt] = __builtin_amdgcn_mfma_f32_16x16x32_bf16(pf, vf_l, O[nt], 0, 0, 0);
        }
        Ol = __builtin_amdgcn_mfma_f32_16x16x32_bf16(pf, onesv, Ol, 0, 0, 0);
    }

    #pragma unroll
    for (int rr = 0; rr < 4; rr++) {
        const float inv = 1.0f / Ol[rr];
        const int qg = q0 + w * 16 + quad * 4 + rr;
        const size_t roff = (size_t)qg * D + h * HD;
        #pragma unroll
        for (int nt = 0; nt < 8; nt++) {
            const float o = O[nt][rr] * inv;
            const ushort_t hv = bf16_rne(o);
            const ushort_t lv = bf16_rne(o - bf16_f32(hv));
            const int hp = __shfl_xor((int)hv, 1);
            const int lp = __shfl_xor((int)lv, 1);
            if (!(lr & 1)) {
                *(uint_t*)&ctxh[roff + nt * 16 + lr] = (uint_t)hv | ((uint_t)hp << 16);
                *(uint_t*)&ctxl[roff + nt * 16 + lr] = (uint_t)lv | ((uint_t)lp << 16);
            }
        }
    }
}

// ---------------------------------------------------------------------------
// Dense GEMM (MFMA, R7 dbuf core): out = ctx @ Wdense + b
// ---------------------------------------------------------------------------
__global__ __launch_bounds__(256) void gemm_dense_mfma(
    const ushort_t* __restrict__ Ah, const ushort_t* __restrict__ Al,
    const ushort_t* __restrict__ Wth, const ushort_t* __restrict__ Wtl,
    const float* __restrict__ bias, float* __restrict__ out)
{
    __shared__ ushort_t lds[2 * 4 * TILE_ELEMS];   // 64 KB
    const int t = threadIdx.x;
    const int col0 = blockIdx.x * 128;
    const int row0 = blockIdx.y * 128;

    f32x4 acc[4][4] = {};
    mm_core_split(Ah + (size_t)row0 * D, Al + (size_t)row0 * D,
                  Wth + (size_t)col0 * D, Wtl + (size_t)col0 * D,
                  D, lds, t, acc);

    const int lane = t & 63;
    const int quad = lane >> 4;
    const int lr   = lane & 15;
    const int wm = ((t >> 6) & 1) * 64;
    const int wn = ((t >> 6) >> 1) * 64;

    #pragma unroll
    for (int nt = 0; nt < 4; nt++) {
        const int n = col0 + wn + nt * 16 + lr;
        const float bsc = bias[n];
        #pragma unroll
        for (int mt = 0; mt < 4; mt++) {
            #pragma unroll
            for (int reg = 0; reg < 4; reg++) {
                const int m = row0 + wm + mt * 16 + quad * 4 + reg;
                const float o = acc[mt][nt][reg] + bsc;
                const float po = __shfl_xor(o, 1);
                if (!(n & 1))
                    *(float2*)&out[(size_t)m * D + n] = make_float2(o, po);
            }
        }
    }
}

// ---------------------------------------------------------------------------
// Fallback f32 path (R2, known-good) for small workspace.
// ---------------------------------------------------------------------------
__global__ __launch_bounds__(256) void gemm_qkv_kernel(
    const float* __restrict__ x, const float* __restrict__ W,
    const float* __restrict__ bias, const float* __restrict__ freqs,
    const int* __restrict__ input_pos,
    float* __restrict__ qb, float* __restrict__ kb, float* __restrict__ vb)
{
    __shared__ float As[16][68];
    __shared__ float Bs[16][64];
    const int bx = blockIdx.x;
    const int by = blockIdx.y;
    const int tid = threadIdx.x;
    const int tx = tid & 15, ty = tid >> 4;
    const int row0 = by * 64, col0 = bx * 64;
    const int am = tid >> 2;
    const int ak = (tid & 3) * 4;
    const int bk = tid >> 4;
    const int bn = (tid & 15) * 4;
    float acc[4][4] = {};
    for (int k0 = 0; k0 < D; k0 += 16) {
        float4 av = *(const float4*)&x[(size_t)(row0 + am) * D + k0 + ak];
        float4 bv = *(const float4*)&W[(size_t)(k0 + bk) * N3 + col0 + bn];
        __syncthreads();
        As[ak + 0][am] = av.x; As[ak + 1][am] = av.y;
        As[ak + 2][am] = av.z; As[ak + 3][am] = av.w;
        *(float4*)&Bs[bk][bn] = bv;
        __syncthreads();
        #pragma unroll
        for (int k = 0; k < 16; k++) {
            float4 a4 = *(const float4*)&As[k][ty * 4];
            float4 b4 = *(const float4*)&Bs[k][tx * 4];
            float a[4] = {a4.x, a4.y, a4.z, a4.w};
            float b[4] = {b4.x, b4.y, b4.z, b4.w};
            #pragma unroll
            for (int r = 0; r < 4; r++)
                #pragma unroll
                for (int c = 0; c < 4; c++)
                    acc[r][c] += a[r] * b[c];
        }
    }
    const int j0 = col0 + tx * 4;
    const int which = j0 >> 11;
    const int hh = (j0 & 2047) >> 7;
    const int d0 = j0 & 127;
    const float bv0 = bias[j0 + 0], bv1 = bias[j0 + 1];
    const float bv2 = bias[j0 + 2], bv3 = bias[j0 + 3];
    #pragma unroll
    for (int r = 0; r < 4; r++) {
        const int grow = row0 + ty * 4 + r;
        float v0 = acc[r][0] + bv0, v1 = acc[r][1] + bv1;
        float v2 = acc[r][2] + bv2, v3 = acc[r][3] + bv3;
        if (which == 2) {
            const int pos = input_pos[grow];
            float4 o4 = make_float4(v0, v1, v2, v3);
            *(float4*)&vb[((size_t)hh * S + pos) * HD + d0] = o4;
        } else {
            const float* fc = &freqs[((size_t)grow * 64 + (d0 >> 1)) * 2];
            float c0 = fc[0], s0 = fc[1], c1 = fc[2], s1 = fc[3];
            float o0 = v0 * c0 - v1 * s0, o1 = v1 * c0 + v0 * s0;
            float o2 = v2 * c1 - v3 * s1, o3 = v3 * c1 + v2 * s1;
            float4 o4 = make_float4(o0, o1, o2, o3);
            if (which == 0) {
                *(float4*)&qb[((size_t)hh * S + grow) * HD + d0] = o4;
            } else {
                const int pos = input_pos[grow];
                *(float4*)&kb[((size_t)hh * S + pos) * HD + d0] = o4;
            }
        }
    }
}

#define BQ 64
#define ABK 32
#define QSTR 132
#define KVSTR 132
#define PSTR 68

__global__ __launch_bounds__(256) void attn_kernel(
    const float* __restrict__ qb, const float* __restrict__ kb,
    const float* __restrict__ vb, float* __restrict__ ctx)
{
    __shared__ float Qs[BQ * QSTR];
    __shared__ float KV[ABK * KVSTR];
    __shared__ float Psf[ABK * PSTR];

    const int pa = blockIdx.x;
    const int h  = blockIdx.y;
    const int t  = threadIdx.x;
    const int ty = t >> 4, tx = t & 15;
    const int i0  = ty * 4;
    const int j0  = tx * 2;
    const int dd0 = tx * 8;
    const int lr = t >> 3;
    const int lc = (t & 7) * 4;

    const float* kbase = kb + (size_t)h * S * HD;
    const float* vbase = vb + (size_t)h * S * HD;
    const float kSc = 0.08838834764831845f * 1.4426950408889634f;

    for (int ph = 0; ph < 2; ph++) {
        const int r = (ph == 0) ? pa : 31 - pa;
        const int q0 = r * BQ;
        const int ntiles = 2 * r + 2;

        #pragma unroll
        for (int pp = 0; pp < 2; pp++) {
            const int iq = lr + pp * 32;
            const float* src = qb + ((size_t)h * S + q0 + iq) * HD;
            #pragma unroll
            for (int ch = 0; ch < 4; ch++)
                *(float4*)&Qs[iq * QSTR + lc + ch * 32] =
                    *(const float4*)&src[lc + ch * 32];
        }

        float O[4][8] = {};
        float m[4], l[4];
        #pragma unroll
        for (int rr = 0; rr < 4; rr++) { m[rr] = -1e30f; l[rr] = 0.f; }

        float4 kpref[4];
        #pragma unroll
        for (int ch = 0; ch < 4; ch++)
            kpref[ch] = *(const float4*)&kbase[(size_t)lr * HD + lc + ch * 32];

        __syncthreads();

        for (int kt = 0; kt < ntiles; kt++) {
            const int k0 = kt * ABK;

            #pragma unroll
            for (int ch = 0; ch < 4; ch++)
                *(float4*)&KV[lr * KVSTR + lc + ch * 32] = kpref[ch];
            __syncthreads();

            float4 vpref[4];
            #pragma unroll
            for (int ch = 0; ch < 4; ch++)
                vpref[ch] = *(const float4*)&vbase[(size_t)(k0 + lr) * HD + lc + ch * 32];

            float acc[4][2] = {};
            #pragma unroll 4
            for (int d0 = 0; d0 < HD; d0 += 4) {
                float4 ka = *(const float4*)&KV[(j0 + 0) * KVSTR + d0];
                float4 kb4 = *(const float4*)&KV[(j0 + 1) * KVSTR + d0];
                #pragma unroll
                for (int rr = 0; rr < 4; rr++) {
                    float4 q4 = *(const float4*)&Qs[(i0 + rr) * QSTR + d0];
                    acc[rr][0] += q4.x * ka.x + q4.y * ka.y + q4.z * ka.z + q4.w * ka.w;
                    acc[rr][1] += q4.x * kb4.x + q4.y * kb4.y + q4.z * kb4.z + q4.w * kb4.w;
                }
            }

            const bool need_mask = (k0 + ABK - 1) > q0;
            float p[4][2], alpha[4];
            #pragma unroll
            for (int rr = 0; rr < 4; rr++) {
                float z0 = acc[rr][0] * kSc;
                float z1 = acc[rr][1] * kSc;
                if (need_mask) {
                    if (k0 + j0 + 0 > q0 + i0 + rr) z0 = -1e30f;
                    if (k0 + j0 + 1 > q0 + i0 + rr) z1 = -1e30f;
                }
                float rmax = fmaxf(z0, z1);
                #pragma unroll
                for (int off = 1; off < 16; off <<= 1)
                    rmax = fmaxf(rmax, __shfl_xor(rmax, off, 16));
                const float nm = fmaxf(m[rr], rmax);
                alpha[rr] = exp2f(m[rr] - nm);
                p[rr][0] = exp2f(z0 - nm);
                p[rr][1] = exp2f(z1 - nm);
                float ts = p[rr][0] + p[rr][1];
                #pragma unroll
                for (int off = 1; off < 16; off <<= 1)
                    ts += __shfl_xor(ts, off, 16);
                l[rr] = l[rr] * alpha[rr] + ts;
                m[rr] = nm;
            }
            __syncthreads();

            #pragma unroll
            for (int ch = 0; ch < 4; ch++)
                *(float4*)&KV[lr * KVSTR + lc + ch * 32] = vpref[ch];
            *(float4*)&Psf[(j0 + 0) * PSTR + i0] =
                make_float4(p[0][0], p[1][0], p[2][0], p[3][0]);
            *(float4*)&Psf[(j0 + 1) * PSTR + i0] =
                make_float4(p[0][1], p[1][1], p[2][1], p[3][1]);
            if (kt + 1 < ntiles) {
                #pragma unroll
                for (int ch = 0; ch < 4; ch++)
                    kpref[ch] = *(const float4*)&kbase[(size_t)(k0 + ABK + lr) * HD + lc + ch * 32];
            }
            __syncthreads();

            #pragma unroll
            for (int rr = 0; rr < 4; rr++)
                #pragma unroll
                for (int c = 0; c < 8; c++)
                    O[rr][c] *= alpha[rr];
            #pragma unroll 4
            for (int j = 0; j < ABK; j++) {
                float4 pj = *(const float4*)&Psf[j * PSTR + i0];
                float4 v0 = *(const float4*)&KV[j * KVSTR + dd0];
                float4 v1 = *(const float4*)&KV[j * KVSTR + dd0 + 4];
                const float pr[4] = {pj.x, pj.y, pj.z, pj.w};
                const float vv[8] = {v0.x, v0.y, v0.z, v0.w, v1.x, v1.y, v1.z, v1.w};
                #pragma unroll
                for (int rr = 0; rr < 4; rr++)
                    #pragma unroll
                    for (int c = 0; c < 8; c++)
                        O[rr][c] += pr[rr] * vv[c];
            }
            __syncthreads();
        }

        #pragma unroll
        for (int rr = 0; rr < 4; rr++) {
            const float inv = 1.0f / l[rr];
            const int qg = q0 + i0 + rr;
            float4 o0 = make_float4(O[rr][0] * inv, O[rr][1] * inv,
                                    O[rr][2] * inv, O[rr][3] * inv);
            float4 o1 = make_float4(O[rr][4] * inv, O[rr][5] * inv,
                                    O[rr][6] * inv, O[rr][7] * inv);
            float* dst = &ctx[((size_t)qg * H + h) * HD + dd0];
            *(float4*)&dst[0] = o0;
            *(float4*)&dst[4] = o1;
        }
        __syncthreads();
    }
}

__global__ __launch_bounds__(256) void gemm_dense_kernel(
    const float* __restrict__ A, const float* __restrict__ W,
    const float* __restrict__ bias, float* __restrict__ out)
{
    __shared__ float As[16][68];
    __shared__ float Bs[16][64];
    const int bx = blockIdx.x;
    const int by = blockIdx.y;
    const int tid = threadIdx.x;
    const int tx = tid & 15, ty = tid >> 4;
    const int row0 = by * 64, col0 = bx * 64;
    const int am = tid >> 2;
    const int ak = (tid & 3) * 4;
    const int bk = tid >> 4;
    const int bn = (tid & 15) * 4;
    float acc[4][4] = {};
    for (int k0 = 0; k0 < D; k0 += 16) {
        float4 av = *(const float4*)&A[(size_t)(row0 + am) * D + k0 + ak];
        float4 bv = *(const float4*)&W[(size_t)(k0 + bk) * D + col0 + bn];
        __syncthreads();
        As[ak + 0][am] = av.x; As[ak + 1][am] = av.y;
        As[ak + 2][am] = av.z; As[ak + 3][am] = av.w;
        *(float4*)&Bs[bk][bn] = bv;
        __syncthreads();
        #pragma unroll
        for (int k = 0; k < 16; k++) {
            float4 a4 = *(const float4*)&As[k][ty * 4];
            float4 b4 = *(const float4*)&Bs[k][tx * 4];
            float a[4] = {a4.x, a4.y, a4.z, a4.w};
            float b[4] = {b4.x, b4.y, b4.z, b4.w};
            #pragma unroll
            for (int r = 0; r < 4; r++)
                #pragma unroll
                for (int c = 0; c < 4; c++)
                    acc[r][c] += a[r] * b[c];
        }
    }
    const int j0 = col0 + tx * 4;
    const float bv0 = bias[j0 + 0], bv1 = bias[j0 + 1];
    const float bv2 = bias[j0 + 2], bv3 = bias[j0 + 3];
    #pragma unroll
    for (int r = 0; r < 4; r++) {
        const int grow = row0 + ty * 4 + r;
        float4 o4 = make_float4(acc[r][0] + bv0, acc[r][1] + bv1,
                                acc[r][2] + bv2, acc[r][3] + bv3);
        *(float4*)&out[(size_t)grow * D + j0] = o4;
    }
}

extern "C" void kernel_launch(void* const* d_in, const int* in_sizes, int n_in,
                              void* d_out, int out_size, void* d_ws, size_t ws_size,
                              hipStream_t stream) {
    const float* x      = (const float*)d_in[0];
    const float* freqs  = (const float*)d_in[1];
    const int*   pos    = (const int*)d_in[2];
    const float* Wqkv   = (const float*)d_in[3];
    const float* bqkv   = (const float*)d_in[4];
    const float* Wdense = (const float*)d_in[5];
    const float* bdense = (const float*)d_in[6];
    float* out = (float*)d_out;

    const size_t nSD = (size_t)S * D;   // 4 Mi elems
    const size_t nW1 = (size_t)D * N3;  // 12 Mi elems

    // mfma path ws (all bf16): 12 nSD-sized arrays + 2 nW1-sized = 144 MiB
    const size_t needed = (12 * nSD + 2 * nW1) * sizeof(ushort_t);

    if (ws_size >= needed) {
        ushort_t* qh   = (ushort_t*)d_ws;
        ushort_t* ql   = qh + nSD;
        ushort_t* kh   = ql + nSD;
        ushort_t* kl   = kh + nSD;
        ushort_t* vh   = kl + nSD;
        ushort_t* vl   = vh + nSD;
        ushort_t* ctxh = vl + nSD;
        ushort_t* ctxl = ctxh + nSD;
        ushort_t* xh   = ctxl + nSD;
        ushort_t* xl   = xh + nSD;
        ushort_t* Wth  = xl + nSD;
        ushort_t* Wtl  = Wth + nW1;
        ushort_t* Wdth = Wtl + nW1;
        ushort_t* Wdtl = Wdth + nSD;

        convert_split_kernel<<<nSD / 4 / 256, 256, 0, stream>>>(x, xh, xl);
        dim3 gt1(D / 32, N3 / 32);
        convert_split_t_kernel<<<gt1, 256, 0, stream>>>(Wqkv, Wth, Wtl, D, N3);
        dim3 gt2(D / 32, D / 32);
        convert_split_t_kernel<<<gt2, 256, 0, stream>>>(Wdense, Wdth, Wdtl, D, D);

        dim3 g1(N3 / 128, S / 128);
        gemm_qkv_mfma<<<g1, 256, 0, stream>>>(xh, xl, Wth, Wtl, bqkv, freqs,
                                              pos, qh, ql, kh, kl, vh, vl);
        dim3 g2(32, H);
        attn_mfma_kernel<<<g2, 256, 0, stream>>>(qh, ql, kh, kl, vh, vl,
                                                 ctxh, ctxl);
        dim3 g3(D / 128, S / 128);
        gemm_dense_mfma<<<g3, 256, 0, stream>>>(ctxh, ctxl, Wdth, Wdtl, bdense, out);
    } else {
        // fallback: R2 f32 path (needs only 64 MiB)
        float* qb  = (float*)d_ws;
        float* kb  = qb + (size_t)H * S * HD;
        float* vb  = kb + (size_t)H * S * HD;
        float* ctx = vb + (size_t)H * S * HD;
        dim3 g1(N3 / 64, S / 64);
        gemm_qkv_kernel<<<g1, 256, 0, stream>>>(x, Wqkv, bqkv, freqs, pos, qb, kb, vb);
        dim3 g2(16, H);
        attn_kernel<<<g2, 256, 0, stream>>>(qb, kb, vb, ctx);
        dim3 g3(D / 64, S / 64);
        gemm_dense_kernel<<<g3, 256, 0, stream>>>(ctx, Wdense, bdense, out);
    }
}

// Round 10
// 531.175 us; speedup vs baseline: 1.2034x; 1.0192x over previous
//
#include <hip/hip_runtime.h>

#define S 2048
#define D 2048
#define H 16
#define HD 128
#define N3 6144  // 3*D

typedef __attribute__((ext_vector_type(8))) short bf16x8;
typedef __attribute__((ext_vector_type(4))) float f32x4;
typedef unsigned short ushort_t;
typedef unsigned int uint_t;

// ---------------------------------------------------------------------------
// bf16 split helpers (round-to-nearest-even)
// ---------------------------------------------------------------------------
__device__ __forceinline__ ushort_t bf16_rne(float f) {
    uint_t u = __float_as_uint(f);
    u += 0x7fffu + ((u >> 16) & 1u);
    return (ushort_t)(u >> 16);
}
__device__ __forceinline__ float bf16_f32(ushort_t h) {
    return __uint_as_float(((uint_t)h) << 16);
}

// split f32 row-major -> hi/lo bf16 row-major (same layout)
__global__ __launch_bounds__(256) void convert_split_kernel(
    const float* __restrict__ in, ushort_t* __restrict__ hi,
    ushort_t* __restrict__ lo)
{
    const int i = blockIdx.x * 256 + threadIdx.x;  // per float4
    float4 v = ((const float4*)in)[i];
    ushort_t h0 = bf16_rne(v.x), h1 = bf16_rne(v.y);
    ushort_t h2 = bf16_rne(v.z), h3 = bf16_rne(v.w);
    ushort4 hv = make_ushort4(h0, h1, h2, h3);
    ushort4 lv = make_ushort4(bf16_rne(v.x - bf16_f32(h0)),
                              bf16_rne(v.y - bf16_f32(h1)),
                              bf16_rne(v.z - bf16_f32(h2)),
                              bf16_rne(v.w - bf16_f32(h3)));
    ((ushort4*)hi)[i] = hv;
    ((ushort4*)lo)[i] = lv;
}

// W [K][N] f32 -> Wt hi/lo [N][K] bf16 (transpose + split), 32x32 tiles.
__global__ __launch_bounds__(256) void convert_split_t_kernel(
    const float* __restrict__ in, ushort_t* __restrict__ hi,
    ushort_t* __restrict__ lo, int Kdim, int Ndim)
{
    __shared__ float tile[32][33];
    const int k0 = blockIdx.x * 32, n0 = blockIdx.y * 32;
    const int tx = threadIdx.x & 31, ty = threadIdx.x >> 5;  // ty 0..7
    #pragma unroll
    for (int r = 0; r < 4; r++)
        tile[ty + r * 8][tx] = in[(size_t)(k0 + ty + r * 8) * Ndim + n0 + tx];
    __syncthreads();
    const int n  = threadIdx.x >> 3;        // 0..31 local col
    const int kc = (threadIdx.x & 7) * 4;   // 0..28 local k chunk
    const float v0 = tile[kc + 0][n], v1 = tile[kc + 1][n];
    const float v2 = tile[kc + 2][n], v3 = tile[kc + 3][n];
    const ushort_t h0 = bf16_rne(v0), h1 = bf16_rne(v1);
    const ushort_t h2 = bf16_rne(v2), h3 = bf16_rne(v3);
    const size_t off = (size_t)(n0 + n) * Kdim + k0 + kc;
    *(ushort4*)&hi[off] = make_ushort4(h0, h1, h2, h3);
    *(ushort4*)&lo[off] = make_ushort4(bf16_rne(v0 - bf16_f32(h0)),
                                       bf16_rne(v1 - bf16_f32(h1)),
                                       bf16_rne(v2 - bf16_f32(h2)),
                                       bf16_rne(v3 - bf16_f32(h3)));
}

// ---------------------------------------------------------------------------
// async global->LDS, 16 B per lane, wave-uniform LDS base (HW adds lane*16).
// ---------------------------------------------------------------------------
__device__ __forceinline__ void gload16(const ushort_t* g, ushort_t* l) {
    __builtin_amdgcn_global_load_lds(
        (const __attribute__((address_space(1))) unsigned int*)g,
        (__attribute__((address_space(3))) unsigned int*)l, 16, 0, 0);
}

// ---------------------------------------------------------------------------
// Split-bf16 MFMA GEMM core (R7/R9, verified 210 us qkv): BK=32, 16x16x32,
// double-buffered 64 KB LDS, m97 bank-benign 64 B rows. R8's BK=16/32x32
// interleaved variant REGRESSED (3x conflicts) — do not re-try.
// ---------------------------------------------------------------------------
#define BK 32
#define TILE_ELEMS (128 * BK)

__device__ __forceinline__ void mm_core_split(
    const ushort_t* __restrict__ Agh, const ushort_t* __restrict__ Agl,
    const ushort_t* __restrict__ Bgh, const ushort_t* __restrict__ Bgl,
    const int K, ushort_t* lds, const int t, f32x4 (&acc)[4][4])
{
    const int lane = t & 63;
    const int wv   = t >> 6;
    const int lrow = lane >> 2;
    const int lk   = (lane & 3) * 8;
    const int quad = lane >> 4;
    const int lr   = lane & 15;
    const int wm   = (wv & 1) * 64;
    const int wn   = (wv >> 1) * 64;

    const int r0  = wv * 16;
    const int lo0 = r0 * BK;
    const int lo1 = (r0 + 64) * BK;

    auto stage = [&](int k0, int buf) {
        ushort_t* base = lds + buf * 4 * TILE_ELEMS;
        ushort_t* As_h = base;
        ushort_t* As_l = base + TILE_ELEMS;
        ushort_t* Bs_h = base + 2 * TILE_ELEMS;
        ushort_t* Bs_l = base + 3 * TILE_ELEMS;
        const size_t go0 = (size_t)(r0 + lrow) * K + k0 + lk;
        const size_t go1 = (size_t)(r0 + 64 + lrow) * K + k0 + lk;
        gload16(Agh + go0, As_h + lo0);
        gload16(Agh + go1, As_h + lo1);
        gload16(Agl + go0, As_l + lo0);
        gload16(Agl + go1, As_l + lo1);
        gload16(Bgh + go0, Bs_h + lo0);
        gload16(Bgh + go1, Bs_h + lo1);
        gload16(Bgl + go0, Bs_l + lo0);
        gload16(Bgl + go1, Bs_l + lo1);
    };

    stage(0, 0);

    const int niter = K / BK;
    for (int it = 0; it < niter; it++) {
        const int cur = it & 1;
        __syncthreads();  // drains vmcnt: tile it visible; buf cur^1 free

        if (it + 1 < niter) stage((it + 1) * BK, cur ^ 1);

        ushort_t* base = lds + cur * 4 * TILE_ELEMS;
        ushort_t* As_h = base;
        ushort_t* As_l = base + TILE_ELEMS;
        ushort_t* Bs_h = base + 2 * TILE_ELEMS;
        ushort_t* Bs_l = base + 3 * TILE_ELEMS;

        bf16x8 af_h[4], af_l[4], bf_h[4], bf_l[4];
        #pragma unroll
        for (int i = 0; i < 4; i++) {
            af_h[i] = *(const bf16x8*)&As_h[(wm + i * 16 + lr) * BK + quad * 8];
            af_l[i] = *(const bf16x8*)&As_l[(wm + i * 16 + lr) * BK + quad * 8];
            bf_h[i] = *(const bf16x8*)&Bs_h[(wn + i * 16 + lr) * BK + quad * 8];
            bf_l[i] = *(const bf16x8*)&Bs_l[(wn + i * 16 + lr) * BK + quad * 8];
        }
        #pragma unroll
        for (int mt = 0; mt < 4; mt++)
            #pragma unroll
            for (int nt = 0; nt < 4; nt++) {
                acc[mt][nt] = __builtin_amdgcn_mfma_f32_16x16x32_bf16(
                    af_h[mt], bf_h[nt], acc[mt][nt], 0, 0, 0);
                acc[mt][nt] = __builtin_amdgcn_mfma_f32_16x16x32_bf16(
                    af_h[mt], bf_l[nt], acc[mt][nt], 0, 0, 0);
                acc[mt][nt] = __builtin_amdgcn_mfma_f32_16x16x32_bf16(
                    af_l[mt], bf_h[nt], acc[mt][nt], 0, 0, 0);
            }
    }
}

// ---------------------------------------------------------------------------
// QKV GEMM (MFMA) with split-bf16 outputs (R7/R9 epilogue).
// ---------------------------------------------------------------------------
__global__ __launch_bounds__(256) void gemm_qkv_mfma(
    const ushort_t* __restrict__ xh, const ushort_t* __restrict__ xl,
    const ushort_t* __restrict__ Wth, const ushort_t* __restrict__ Wtl,
    const float* __restrict__ bias, const float* __restrict__ freqs,
    const int* __restrict__ input_pos,
    ushort_t* __restrict__ qhg, ushort_t* __restrict__ qlg,
    ushort_t* __restrict__ khg, ushort_t* __restrict__ klg,
    ushort_t* __restrict__ vhg, ushort_t* __restrict__ vlg)
{
    __shared__ ushort_t lds[2 * 4 * TILE_ELEMS];   // 64 KB
    const int t = threadIdx.x;
    const int col0 = blockIdx.x * 128;
    const int row0 = blockIdx.y * 128;

    f32x4 acc[4][4] = {};
    mm_core_split(xh + (size_t)row0 * D, xl + (size_t)row0 * D,
                  Wth + (size_t)col0 * D, Wtl + (size_t)col0 * D,
                  D, lds, t, acc);

    const int lane = t & 63;
    const int quad = lane >> 4;
    const int lr   = lane & 15;
    const int wm = ((t >> 6) & 1) * 64;
    const int wn = ((t >> 6) >> 1) * 64;

    const int which = col0 >> 11;           // 0=q 1=k 2=v
    const int hh = (col0 & 2047) >> 7;

    if (which == 2) {
        ushort_t* vh_b = vhg + (size_t)hh * HD * S;
        ushort_t* vl_b = vlg + (size_t)hh * HD * S;
        #pragma unroll
        for (int nt = 0; nt < 4; nt++) {
            const int d = wn + nt * 16 + lr;
            const float bsc = bias[col0 + d];
            #pragma unroll
            for (int mt = 0; mt < 4; mt++) {
                #pragma unroll
                for (int reg = 0; reg < 4; reg++) {
                    const int m = row0 + wm + mt * 16 + quad * 4 + reg;
                    const float v = acc[mt][nt][reg] + bsc;
                    const ushort_t hv = bf16_rne(v);
                    const ushort_t lv = bf16_rne(v - bf16_f32(hv));
                    const int pos = input_pos[m];
                    vh_b[(size_t)d * S + pos] = hv;
                    vl_b[(size_t)d * S + pos] = lv;
                }
            }
        }
    } else {
        ushort_t* oh_b = ((which == 0) ? qhg : khg) + (size_t)hh * S * HD;
        ushort_t* ol_b = ((which == 0) ? qlg : klg) + (size_t)hh * S * HD;
        #pragma unroll
        for (int nt = 0; nt < 4; nt++) {
            const int d = wn + nt * 16 + lr;
            const float bsc = bias[col0 + d];
            #pragma unroll
            for (int mt = 0; mt < 4; mt++) {
                #pragma unroll
                for (int reg = 0; reg < 4; reg++) {
                    const int m = row0 + wm + mt * 16 + quad * 4 + reg;
                    const float v = acc[mt][nt][reg] + bsc;
                    const float* fc = &freqs[((size_t)m * 64 + (d >> 1)) * 2];
                    const float c = fc[0], s = fc[1];
                    const float p = __shfl_xor(v, 1);
                    const float o = (d & 1) ? (v * c + p * s) : (v * c - p * s);
                    const ushort_t hv = bf16_rne(o);
                    const ushort_t lv = bf16_rne(o - bf16_f32(hv));
                    const int hp = __shfl_xor((int)hv, 1);
                    const int lp = __shfl_xor((int)lv, 1);
                    if (!(d & 1)) {
                        const int srow = (which == 0) ? m : input_pos[m];
                        *(uint_t*)&oh_b[(size_t)srow * HD + d] =
                            (uint_t)hv | ((uint_t)hp << 16);
                        *(uint_t*)&ol_b[(size_t)srow * HD + d] =
                            (uint_t)lv | ((uint_t)lp << 16);
                    }
                }
            }
        }
    }
}

// ---------------------------------------------------------------------------
// MFMA flash attention, R10: R9 structure (dbuf, ones-column l) + XCD-aware
// block swizzle. 1-D grid of 512; with the round-robin blockIdx->XCD
// heuristic (xcd = bi%8), heads {c, c+8} x all 32 q-tiles land on XCD c:
// working set = K/V of 2 heads = 4 MB = one XCD L2 -> staging drains hit L2
// (~200 cyc) instead of HBM (~900). Mapping is a locality heuristic only —
// correctness does not depend on it (G16). Consecutive same-XCD blocks pair
// r and 31-r so per-CU tile work stays balanced.
// ---------------------------------------------------------------------------
__global__ __launch_bounds__(256, 2) void attn_mfma_kernel(
    const ushort_t* __restrict__ qhg, const ushort_t* __restrict__ qlg,
    const ushort_t* __restrict__ khg, const ushort_t* __restrict__ klg,
    const ushort_t* __restrict__ vhg, const ushort_t* __restrict__ vlg,
    ushort_t* __restrict__ ctxh, ushort_t* __restrict__ ctxl)
{
    __shared__ ushort_t Khs[2][4096];   // [buf][ks*1024 + key*32 + d8]
    __shared__ ushort_t Kls[2][4096];
    __shared__ ushort_t Vhs[2][4096];   // [buf][dim*32 + key8]
    __shared__ ushort_t Vls[2][4096];
    __shared__ ushort_t Ps[64 * 32];

    const int bi = blockIdx.x;             // 0..511
    const int h  = (bi & 7) + 8 * ((bi >> 3) & 1);
    const int qi = bi >> 4;                // 0..31
    const int r = (h & 8) ? qi : (31 - qi);
    const int q0 = r * 64;
    const int ntiles = 2 * r + 2;
    const int t = threadIdx.x;
    const int w = t >> 6, lane = t & 63;
    const int lr = lane & 15, quad = lane >> 4;

    const size_t qrow = (size_t)h * S + q0 + w * 16 + lr;
    bf16x8 qf_h[4], qf_l[4];
    #pragma unroll
    for (int ks = 0; ks < 4; ks++) {
        qf_h[ks] = *(const bf16x8*)&qhg[qrow * HD + ks * 32 + quad * 8];
        qf_l[ks] = *(const bf16x8*)&qlg[qrow * HD + ks * 32 + quad * 8];
    }

    const ushort_t* kh_b = khg + (size_t)h * S * HD;
    const ushort_t* kl_b = klg + (size_t)h * S * HD;
    const ushort_t* vh_b = vhg + (size_t)h * HD * S;
    const ushort_t* vl_b = vlg + (size_t)h * HD * S;

    const int keyq = lane >> 2;   // 0..15
    const int sub  = lane & 3;    // 16B chunk index

    auto stage = [&](int kt, int buf) {
        const int k0 = kt * 32;
        #pragma unroll
        for (int hf = 0; hf < 2; hf++) {
            const size_t ksrc = (size_t)(k0 + hf * 16 + keyq) * HD + w * 32 + sub * 8;
            gload16(kh_b + ksrc, &Khs[buf][w * 1024 + hf * 512]);
            gload16(kl_b + ksrc, &Kls[buf][w * 1024 + hf * 512]);
            const int dim = w * 32 + hf * 16 + keyq;
            const size_t vsrc = (size_t)dim * S + k0 + sub * 8;
            gload16(vh_b + vsrc, &Vhs[buf][(w * 32 + hf * 16) * 32]);
            gload16(vl_b + vsrc, &Vls[buf][(w * 32 + hf * 16) * 32]);
        }
    };

    f32x4 O[8] = {};
    f32x4 Ol = {0.f, 0.f, 0.f, 0.f};   // ones-column: per-row softmax denom
    float mrow[4];
    #pragma unroll
    for (int rr = 0; rr < 4; rr++) mrow[rr] = -1e30f;

    bf16x8 onesv;
    #pragma unroll
    for (int i = 0; i < 8; i++) onesv[i] = (short)0x3F80;   // bf16 1.0

    const float kSc = 0.08838834764831845f * 1.4426950408889634f; // scale*log2e

    stage(0, 0);

    for (int kt = 0; kt < ntiles; kt++) {
        const int k0 = kt * 32;
        const int cur = kt & 1;
        __syncthreads();  // drains vmcnt -> tile kt visible; buf cur^1 free

        if (kt + 1 < ntiles) stage(kt + 1, cur ^ 1);

        f32x4 sa[2];
        #pragma unroll
        for (int nt = 0; nt < 2; nt++) {
            f32x4 s = {0.f, 0.f, 0.f, 0.f};
            #pragma unroll
            for (int ks = 0; ks < 4; ks++) {
                bf16x8 kf_h = *(const bf16x8*)&Khs[cur][ks * 1024 + (nt * 16 + lr) * 32 + quad * 8];
                bf16x8 kf_l = *(const bf16x8*)&Kls[cur][ks * 1024 + (nt * 16 + lr) * 32 + quad * 8];
                s = __builtin_amdgcn_mfma_f32_16x16x32_bf16(qf_h[ks], kf_h, s, 0, 0, 0);
                s = __builtin_amdgcn_mfma_f32_16x16x32_bf16(qf_l[ks], kf_h, s, 0, 0, 0);
                s = __builtin_amdgcn_mfma_f32_16x16x32_bf16(qf_h[ks], kf_l, s, 0, 0, 0);
            }
            sa[nt] = s;
        }

        const int rowbase = q0 + w * 16 + quad * 4;
        const bool need_mask = (k0 + 31) > (q0 + w * 16);
        float alpha[4], pv0[4], pv1[4];
        #pragma unroll
        for (int rr = 0; rr < 4; rr++) {
            float z0 = sa[0][rr] * kSc;
            float z1 = sa[1][rr] * kSc;
            if (need_mask) {
                const int rowg = rowbase + rr;
                if (k0 + lr > rowg)      z0 = -1e30f;
                if (k0 + 16 + lr > rowg) z1 = -1e30f;
            }
            float rm = fmaxf(z0, z1);
            #pragma unroll
            for (int off = 1; off < 16; off <<= 1)
                rm = fmaxf(rm, __shfl_xor(rm, off));
            const float nm = fmaxf(mrow[rr], rm);
            alpha[rr] = exp2f(mrow[rr] - nm);
            pv0[rr] = exp2f(z0 - nm);
            pv1[rr] = exp2f(z1 - nm);
            mrow[rr] = nm;
        }

        #pragma unroll
        for (int rr = 0; rr < 4; rr++) {
            const int prow = (w * 16 + quad * 4 + rr) * 32;
            Ps[prow + lr]      = bf16_rne(pv0[rr]);
            Ps[prow + 16 + lr] = bf16_rne(pv1[rr]);
        }
        // no barrier: each wave reads only its own P rows (lgkmcnt orders)

        #pragma unroll
        for (int nt = 0; nt < 8; nt++)
            #pragma unroll
            for (int rr = 0; rr < 4; rr++)
                O[nt][rr] *= alpha[rr];
        #pragma unroll
        for (int rr = 0; rr < 4; rr++)
            Ol[rr] *= alpha[rr];
        const bf16x8 pf = *(const bf16x8*)&Ps[(w * 16 + lr) * 32 + quad * 8];
        #pragma unroll
        for (int nt = 0; nt < 8; nt++) {
            bf16x8 vf_h = *(const bf16x8*)&Vhs[cur][(nt * 16 + lr) * 32 + quad * 8];
            bf16x8 vf_l = *(const bf16x8*)&Vls[cur][(nt * 16 + lr) * 32 + quad * 8];
            O[nt] = __builtin_amdgcn_mfma_f32_16x16x32_bf16(pf, vf_h, O[nt], 0, 0, 0);
            O[nt] = __builtin_amdgcn_mfma_f32_16x16x32_bf16(pf, vf_l, O[nt], 0, 0, 0);
        }
        Ol = __builtin_amdgcn_mfma_f32_16x16x32_bf16(pf, onesv, Ol, 0, 0, 0);
    }

    #pragma unroll
    for (int rr = 0; rr < 4; rr++) {
        const float inv = 1.0f / Ol[rr];
        const int qg = q0 + w * 16 + quad * 4 + rr;
        const size_t roff = (size_t)qg * D + h * HD;
        #pragma unroll
        for (int nt = 0; nt < 8; nt++) {
            const float o = O[nt][rr] * inv;
            const ushort_t hv = bf16_rne(o);
            const ushort_t lv = bf16_rne(o - bf16_f32(hv));
            const int hp = __shfl_xor((int)hv, 1);
            const int lp = __shfl_xor((int)lv, 1);
            if (!(lr & 1)) {
                *(uint_t*)&ctxh[roff + nt * 16 + lr] = (uint_t)hv | ((uint_t)hp << 16);
                *(uint_t*)&ctxl[roff + nt * 16 + lr] = (uint_t)lv | ((uint_t)lp << 16);
            }
        }
    }
}

// ---------------------------------------------------------------------------
// Dense GEMM (MFMA, R7/R9 dbuf core): out = ctx @ Wdense + b
// ---------------------------------------------------------------------------
__global__ __launch_bounds__(256) void gemm_dense_mfma(
    const ushort_t* __restrict__ Ah, const ushort_t* __restrict__ Al,
    const ushort_t* __restrict__ Wth, const ushort_t* __restrict__ Wtl,
    const float* __restrict__ bias, float* __restrict__ out)
{
    __shared__ ushort_t lds[2 * 4 * TILE_ELEMS];   // 64 KB
    const int t = threadIdx.x;
    const int col0 = blockIdx.x * 128;
    const int row0 = blockIdx.y * 128;

    f32x4 acc[4][4] = {};
    mm_core_split(Ah + (size_t)row0 * D, Al + (size_t)row0 * D,
                  Wth + (size_t)col0 * D, Wtl + (size_t)col0 * D,
                  D, lds, t, acc);

    const int lane = t & 63;
    const int quad = lane >> 4;
    const int lr   = lane & 15;
    const int wm = ((t >> 6) & 1) * 64;
    const int wn = ((t >> 6) >> 1) * 64;

    #pragma unroll
    for (int nt = 0; nt < 4; nt++) {
        const int n = col0 + wn + nt * 16 + lr;
        const float bsc = bias[n];
        #pragma unroll
        for (int mt = 0; mt < 4; mt++) {
            #pragma unroll
            for (int reg = 0; reg < 4; reg++) {
                const int m = row0 + wm + mt * 16 + quad * 4 + reg;
                const float o = acc[mt][nt][reg] + bsc;
                const float po = __shfl_xor(o, 1);
                if (!(n & 1))
                    *(float2*)&out[(size_t)m * D + n] = make_float2(o, po);
            }
        }
    }
}

// ---------------------------------------------------------------------------
// Fallback f32 path (R2, known-good) for small workspace.
// ---------------------------------------------------------------------------
__global__ __launch_bounds__(256) void gemm_qkv_kernel(
    const float* __restrict__ x, const float* __restrict__ W,
    const float* __restrict__ bias, const float* __restrict__ freqs,
    const int* __restrict__ input_pos,
    float* __restrict__ qb, float* __restrict__ kb, float* __restrict__ vb)
{
    __shared__ float As[16][68];
    __shared__ float Bs[16][64];
    const int bx = blockIdx.x;
    const int by = blockIdx.y;
    const int tid = threadIdx.x;
    const int tx = tid & 15, ty = tid >> 4;
    const int row0 = by * 64, col0 = bx * 64;
    const int am = tid >> 2;
    const int ak = (tid & 3) * 4;
    const int bk = tid >> 4;
    const int bn = (tid & 15) * 4;
    float acc[4][4] = {};
    for (int k0 = 0; k0 < D; k0 += 16) {
        float4 av = *(const float4*)&x[(size_t)(row0 + am) * D + k0 + ak];
        float4 bv = *(const float4*)&W[(size_t)(k0 + bk) * N3 + col0 + bn];
        __syncthreads();
        As[ak + 0][am] = av.x; As[ak + 1][am] = av.y;
        As[ak + 2][am] = av.z; As[ak + 3][am] = av.w;
        *(float4*)&Bs[bk][bn] = bv;
        __syncthreads();
        #pragma unroll
        for (int k = 0; k < 16; k++) {
            float4 a4 = *(const float4*)&As[k][ty * 4];
            float4 b4 = *(const float4*)&Bs[k][tx * 4];
            float a[4] = {a4.x, a4.y, a4.z, a4.w};
            float b[4] = {b4.x, b4.y, b4.z, b4.w};
            #pragma unroll
            for (int r = 0; r < 4; r++)
                #pragma unroll
                for (int c = 0; c < 4; c++)
                    acc[r][c] += a[r] * b[c];
        }
    }
    const int j0 = col0 + tx * 4;
    const int which = j0 >> 11;
    const int hh = (j0 & 2047) >> 7;
    const int d0 = j0 & 127;
    const float bv0 = bias[j0 + 0], bv1 = bias[j0 + 1];
    const float bv2 = bias[j0 + 2], bv3 = bias[j0 + 3];
    #pragma unroll
    for (int r = 0; r < 4; r++) {
        const int grow = row0 + ty * 4 + r;
        float v0 = acc[r][0] + bv0, v1 = acc[r][1] + bv1;
        float v2 = acc[r][2] + bv2, v3 = acc[r][3] + bv3;
        if (which == 2) {
            const int pos = input_pos[grow];
            float4 o4 = make_float4(v0, v1, v2, v3);
            *(float4*)&vb[((size_t)hh * S + pos) * HD + d0] = o4;
        } else {
            const float* fc = &freqs[((size_t)grow * 64 + (d0 >> 1)) * 2];
            float c0 = fc[0], s0 = fc[1], c1 = fc[2], s1 = fc[3];
            float o0 = v0 * c0 - v1 * s0, o1 = v1 * c0 + v0 * s0;
            float o2 = v2 * c1 - v3 * s1, o3 = v3 * c1 + v2 * s1;
            float4 o4 = make_float4(o0, o1, o2, o3);
            if (which == 0) {
                *(float4*)&qb[((size_t)hh * S + grow) * HD + d0] = o4;
            } else {
                const int pos = input_pos[grow];
                *(float4*)&kb[((size_t)hh * S + pos) * HD + d0] = o4;
            }
        }
    }
}

#define BQ 64
#define ABK 32
#define QSTR 132
#define KVSTR 132
#define PSTR 68

__global__ __launch_bounds__(256) void attn_kernel(
    const float* __restrict__ qb, const float* __restrict__ kb,
    const float* __restrict__ vb, float* __restrict__ ctx)
{
    __shared__ float Qs[BQ * QSTR];
    __shared__ float KV[ABK * KVSTR];
    __shared__ float Psf[ABK * PSTR];

    const int pa = blockIdx.x;
    const int h  = blockIdx.y;
    const int t  = threadIdx.x;
    const int ty = t >> 4, tx = t & 15;
    const int i0  = ty * 4;
    const int j0  = tx * 2;
    const int dd0 = tx * 8;
    const int lr = t >> 3;
    const int lc = (t & 7) * 4;

    const float* kbase = kb + (size_t)h * S * HD;
    const float* vbase = vb + (size_t)h * S * HD;
    const float kSc = 0.08838834764831845f * 1.4426950408889634f;

    for (int ph = 0; ph < 2; ph++) {
        const int r = (ph == 0) ? pa : 31 - pa;
        const int q0 = r * BQ;
        const int ntiles = 2 * r + 2;

        #pragma unroll
        for (int pp = 0; pp < 2; pp++) {
            const int iq = lr + pp * 32;
            const float* src = qb + ((size_t)h * S + q0 + iq) * HD;
            #pragma unroll
            for (int ch = 0; ch < 4; ch++)
                *(float4*)&Qs[iq * QSTR + lc + ch * 32] =
                    *(const float4*)&src[lc + ch * 32];
        }

        float O[4][8] = {};
        float m[4], l[4];
        #pragma unroll
        for (int rr = 0; rr < 4; rr++) { m[rr] = -1e30f; l[rr] = 0.f; }

        float4 kpref[4];
        #pragma unroll
        for (int ch = 0; ch < 4; ch++)
            kpref[ch] = *(const float4*)&kbase[(size_t)lr * HD + lc + ch * 32];

        __syncthreads();

        for (int kt = 0; kt < ntiles; kt++) {
            const int k0 = kt * ABK;

            #pragma unroll
            for (int ch = 0; ch < 4; ch++)
                *(float4*)&KV[lr * KVSTR + lc + ch * 32] = kpref[ch];
            __syncthreads();

            float4 vpref[4];
            #pragma unroll
            for (int ch = 0; ch < 4; ch++)
                vpref[ch] = *(const float4*)&vbase[(size_t)(k0 + lr) * HD + lc + ch * 32];

            float acc[4][2] = {};
            #pragma unroll 4
            for (int d0 = 0; d0 < HD; d0 += 4) {
                float4 ka = *(const float4*)&KV[(j0 + 0) * KVSTR + d0];
                float4 kb4 = *(const float4*)&KV[(j0 + 1) * KVSTR + d0];
                #pragma unroll
                for (int rr = 0; rr < 4; rr++) {
                    float4 q4 = *(const float4*)&Qs[(i0 + rr) * QSTR + d0];
                    acc[rr][0] += q4.x * ka.x + q4.y * ka.y + q4.z * ka.z + q4.w * ka.w;
                    acc[rr][1] += q4.x * kb4.x + q4.y * kb4.y + q4.z * kb4.z + q4.w * kb4.w;
                }
            }

            const bool need_mask = (k0 + ABK - 1) > q0;
            float p[4][2], alpha[4];
            #pragma unroll
            for (int rr = 0; rr < 4; rr++) {
                float z0 = acc[rr][0] * kSc;
                float z1 = acc[rr][1] * kSc;
                if (need_mask) {
                    if (k0 + j0 + 0 > q0 + i0 + rr) z0 = -1e30f;
                    if (k0 + j0 + 1 > q0 + i0 + rr) z1 = -1e30f;
                }
                float rmax = fmaxf(z0, z1);
                #pragma unroll
                for (int off = 1; off < 16; off <<= 1)
                    rmax = fmaxf(rmax, __shfl_xor(rmax, off, 16));
                const float nm = fmaxf(m[rr], rmax);
                alpha[rr] = exp2f(m[rr] - nm);
                p[rr][0] = exp2f(z0 - nm);
                p[rr][1] = exp2f(z1 - nm);
                float ts = p[rr][0] + p[rr][1];
                #pragma unroll
                for (int off = 1; off < 16; off <<= 1)
                    ts += __shfl_xor(ts, off, 16);
                l[rr] = l[rr] * alpha[rr] + ts;
                m[rr] = nm;
            }
            __syncthreads();

            #pragma unroll
            for (int ch = 0; ch < 4; ch++)
                *(float4*)&KV[lr * KVSTR + lc + ch * 32] = vpref[ch];
            *(float4*)&Psf[(j0 + 0) * PSTR + i0] =
                make_float4(p[0][0], p[1][0], p[2][0], p[3][0]);
            *(float4*)&Psf[(j0 + 1) * PSTR + i0] =
                make_float4(p[0][1], p[1][1], p[2][1], p[3][1]);
            if (kt + 1 < ntiles) {
                #pragma unroll
                for (int ch = 0; ch < 4; ch++)
                    kpref[ch] = *(const float4*)&kbase[(size_t)(k0 + ABK + lr) * HD + lc + ch * 32];
            }
            __syncthreads();

            #pragma unroll
            for (int rr = 0; rr < 4; rr++)
                #pragma unroll
                for (int c = 0; c < 8; c++)
                    O[rr][c] *= alpha[rr];
            #pragma unroll 4
            for (int j = 0; j < ABK; j++) {
                float4 pj = *(const float4*)&Psf[j * PSTR + i0];
                float4 v0 = *(const float4*)&KV[j * KVSTR + dd0];
                float4 v1 = *(const float4*)&KV[j * KVSTR + dd0 + 4];
                const float pr[4] = {pj.x, pj.y, pj.z, pj.w};
                const float vv[8] = {v0.x, v0.y, v0.z, v0.w, v1.x, v1.y, v1.z, v1.w};
                #pragma unroll
                for (int rr = 0; rr < 4; rr++)
                    #pragma unroll
                    for (int c = 0; c < 8; c++)
                        O[rr][c] += pr[rr] * vv[c];
            }
            __syncthreads();
        }

        #pragma unroll
        for (int rr = 0; rr < 4; rr++) {
            const float inv = 1.0f / l[rr];
            const int qg = q0 + i0 + rr;
            float4 o0 = make_float4(O[rr][0] * inv, O[rr][1] * inv,
                                    O[rr][2] * inv, O[rr][3] * inv);
            float4 o1 = make_float4(O[rr][4] * inv, O[rr][5] * inv,
                                    O[rr][6] * inv, O[rr][7] * inv);
            float* dst = &ctx[((size_t)qg * H + h) * HD + dd0];
            *(float4*)&dst[0] = o0;
            *(float4*)&dst[4] = o1;
        }
        __syncthreads();
    }
}

__global__ __launch_bounds__(256) void gemm_dense_kernel(
    const float* __restrict__ A, const float* __restrict__ W,
    const float* __restrict__ bias, float* __restrict__ out)
{
    __shared__ float As[16][68];
    __shared__ float Bs[16][64];
    const int bx = blockIdx.x;
    const int by = blockIdx.y;
    const int tid = threadIdx.x;
    const int tx = tid & 15, ty = tid >> 4;
    const int row0 = by * 64, col0 = bx * 64;
    const int am = tid >> 2;
    const int ak = (tid & 3) * 4;
    const int bk = tid >> 4;
    const int bn = (tid & 15) * 4;
    float acc[4][4] = {};
    for (int k0 = 0; k0 < D; k0 += 16) {
        float4 av = *(const float4*)&A[(size_t)(row0 + am) * D + k0 + ak];
        float4 bv = *(const float4*)&W[(size_t)(k0 + bk) * D + col0 + bn];
        __syncthreads();
        As[ak + 0][am] = av.x; As[ak + 1][am] = av.y;
        As[ak + 2][am] = av.z; As[ak + 3][am] = av.w;
        *(float4*)&Bs[bk][bn] = bv;
        __syncthreads();
        #pragma unroll
        for (int k = 0; k < 16; k++) {
            float4 a4 = *(const float4*)&As[k][ty * 4];
            float4 b4 = *(const float4*)&Bs[k][tx * 4];
            float a[4] = {a4.x, a4.y, a4.z, a4.w};
            float b[4] = {b4.x, b4.y, b4.z, b4.w};
            #pragma unroll
            for (int r = 0; r < 4; r++)
                #pragma unroll
                for (int c = 0; c < 4; c++)
                    acc[r][c] += a[r] * b[c];
        }
    }
    const int j0 = col0 + tx * 4;
    const float bv0 = bias[j0 + 0], bv1 = bias[j0 + 1];
    const float bv2 = bias[j0 + 2], bv3 = bias[j0 + 3];
    #pragma unroll
    for (int r = 0; r < 4; r++) {
        const int grow = row0 + ty * 4 + r;
        float4 o4 = make_float4(acc[r][0] + bv0, acc[r][1] + bv1,
                                acc[r][2] + bv2, acc[r][3] + bv3);
        *(float4*)&out[(size_t)grow * D + j0] = o4;
    }
}

extern "C" void kernel_launch(void* const* d_in, const int* in_sizes, int n_in,
                              void* d_out, int out_size, void* d_ws, size_t ws_size,
                              hipStream_t stream) {
    const float* x      = (const float*)d_in[0];
    const float* freqs  = (const float*)d_in[1];
    const int*   pos    = (const int*)d_in[2];
    const float* Wqkv   = (const float*)d_in[3];
    const float* bqkv   = (const float*)d_in[4];
    const float* Wdense = (const float*)d_in[5];
    const float* bdense = (const float*)d_in[6];
    float* out = (float*)d_out;

    const size_t nSD = (size_t)S * D;   // 4 Mi elems
    const size_t nW1 = (size_t)D * N3;  // 12 Mi elems

    // mfma path ws (all bf16): 12 nSD-sized arrays + 2 nW1-sized = 144 MiB
    const size_t needed = (12 * nSD + 2 * nW1) * sizeof(ushort_t);

    if (ws_size >= needed) {
        ushort_t* qh   = (ushort_t*)d_ws;
        ushort_t* ql   = qh + nSD;
        ushort_t* kh   = ql + nSD;
        ushort_t* kl   = kh + nSD;
        ushort_t* vh   = kl + nSD;
        ushort_t* vl   = vh + nSD;
        ushort_t* ctxh = vl + nSD;
        ushort_t* ctxl = ctxh + nSD;
        ushort_t* xh   = ctxl + nSD;
        ushort_t* xl   = xh + nSD;
        ushort_t* Wth  = xl + nSD;
        ushort_t* Wtl  = Wth + nW1;
        ushort_t* Wdth = Wtl + nW1;
        ushort_t* Wdtl = Wdth + nSD;

        convert_split_kernel<<<nSD / 4 / 256, 256, 0, stream>>>(x, xh, xl);
        dim3 gt1(D / 32, N3 / 32);
        convert_split_t_kernel<<<gt1, 256, 0, stream>>>(Wqkv, Wth, Wtl, D, N3);
        dim3 gt2(D / 32, D / 32);
        convert_split_t_kernel<<<gt2, 256, 0, stream>>>(Wdense, Wdth, Wdtl, D, D);

        dim3 g1(N3 / 128, S / 128);
        gemm_qkv_mfma<<<g1, 256, 0, stream>>>(xh, xl, Wth, Wtl, bqkv, freqs,
                                              pos, qh, ql, kh, kl, vh, vl);
        attn_mfma_kernel<<<512, 256, 0, stream>>>(qh, ql, kh, kl, vh, vl,
                                                  ctxh, ctxl);
        dim3 g3(D / 128, S / 128);
        gemm_dense_mfma<<<g3, 256, 0, stream>>>(ctxh, ctxl, Wdth, Wdtl, bdense, out);
    } else {
        // fallback: R2 f32 path (needs only 64 MiB)
        float* qb  = (float*)d_ws;
        float* kb  = qb + (size_t)H * S * HD;
        float* vb  = kb + (size_t)H * S * HD;
        float* ctx = vb + (size_t)H * S * HD;
        dim3 g1(N3 / 64, S / 64);
        gemm_qkv_kernel<<<g1, 256, 0, stream>>>(x, Wqkv, bqkv, freqs, pos, qb, kb, vb);
        dim3 g2(16, H);
        attn_kernel<<<g2, 256, 0, stream>>>(qb, kb, vb, ctx);
        dim3 g3(D / 64, S / 64);
        gemm_dense_kernel<<<g3, 256, 0, stream>>>(ctx, Wdense, bdense, out);
    }
}

// Round 11
// 495.029 us; speedup vs baseline: 1.2913x; 1.0730x over previous
//
#include <hip/hip_runtime.h>

#define S 2048
#define D 2048
#define H 16
#define HD 128
#define N3 6144  // 3*D

typedef __attribute__((ext_vector_type(8))) short bf16x8;
typedef __attribute__((ext_vector_type(4))) float f32x4;
typedef unsigned short ushort_t;
typedef unsigned int uint_t;

// ---------------------------------------------------------------------------
// bf16 split helpers (round-to-nearest-even)
// ---------------------------------------------------------------------------
__device__ __forceinline__ ushort_t bf16_rne(float f) {
    uint_t u = __float_as_uint(f);
    u += 0x7fffu + ((u >> 16) & 1u);
    return (ushort_t)(u >> 16);
}
__device__ __forceinline__ float bf16_f32(ushort_t h) {
    return __uint_as_float(((uint_t)h) << 16);
}

// f32 row-major -> hi bf16 only (for activations; lo term dropped in R11)
__global__ __launch_bounds__(256) void convert_hi_kernel(
    const float* __restrict__ in, ushort_t* __restrict__ hi)
{
    const int i = blockIdx.x * 256 + threadIdx.x;  // per float4
    float4 v = ((const float4*)in)[i];
    ((ushort4*)hi)[i] = make_ushort4(bf16_rne(v.x), bf16_rne(v.y),
                                     bf16_rne(v.z), bf16_rne(v.w));
}

// W [K][N] f32 -> Wt hi/lo [N][K] bf16 (transpose + split), 32x32 tiles.
__global__ __launch_bounds__(256) void convert_split_t_kernel(
    const float* __restrict__ in, ushort_t* __restrict__ hi,
    ushort_t* __restrict__ lo, int Kdim, int Ndim)
{
    __shared__ float tile[32][33];
    const int k0 = blockIdx.x * 32, n0 = blockIdx.y * 32;
    const int tx = threadIdx.x & 31, ty = threadIdx.x >> 5;  // ty 0..7
    #pragma unroll
    for (int r = 0; r < 4; r++)
        tile[ty + r * 8][tx] = in[(size_t)(k0 + ty + r * 8) * Ndim + n0 + tx];
    __syncthreads();
    const int n  = threadIdx.x >> 3;        // 0..31 local col
    const int kc = (threadIdx.x & 7) * 4;   // 0..28 local k chunk
    const float v0 = tile[kc + 0][n], v1 = tile[kc + 1][n];
    const float v2 = tile[kc + 2][n], v3 = tile[kc + 3][n];
    const ushort_t h0 = bf16_rne(v0), h1 = bf16_rne(v1);
    const ushort_t h2 = bf16_rne(v2), h3 = bf16_rne(v3);
    const size_t off = (size_t)(n0 + n) * Kdim + k0 + kc;
    *(ushort4*)&hi[off] = make_ushort4(h0, h1, h2, h3);
    *(ushort4*)&lo[off] = make_ushort4(bf16_rne(v0 - bf16_f32(h0)),
                                       bf16_rne(v1 - bf16_f32(h1)),
                                       bf16_rne(v2 - bf16_f32(h2)),
                                       bf16_rne(v3 - bf16_f32(h3)));
}

// ---------------------------------------------------------------------------
// async global->LDS, 16 B per lane, wave-uniform LDS base (HW adds lane*16).
// ---------------------------------------------------------------------------
__device__ __forceinline__ void gload16(const ushort_t* g, ushort_t* l) {
    __builtin_amdgcn_global_load_lds(
        (const __attribute__((address_space(1))) unsigned int*)g,
        (__attribute__((address_space(3))) unsigned int*)l, 16, 0, 0);
}

// ---------------------------------------------------------------------------
// 2-term split GEMM core (R11): C = Ah*(Bh + Bl). Activations single-bf16
// (A-lo term dropped: error ~1e-3 std, see round notes — tolerance probe),
// weights keep hi+lo. vs R9: staging 8->6 gloads/iter, MFMA 48->32/iter,
// LDS 64->48 KB -> 3 blocks/CU. Same verified BK=32/64-B-row/16x16x32
// structure (R8's BK=16 interleave regressed — do not re-try).
// ---------------------------------------------------------------------------
#define BK 32
#define TILE_ELEMS (128 * BK)

__device__ __forceinline__ void mm_core_2t(
    const ushort_t* __restrict__ Agh,
    const ushort_t* __restrict__ Bgh, const ushort_t* __restrict__ Bgl,
    const int K, ushort_t* lds, const int t, f32x4 (&acc)[4][4])
{
    const int lane = t & 63;
    const int wv   = t >> 6;
    const int lrow = lane >> 2;
    const int lk   = (lane & 3) * 8;
    const int quad = lane >> 4;
    const int lr   = lane & 15;
    const int wm   = (wv & 1) * 64;
    const int wn   = (wv >> 1) * 64;

    const int r0  = wv * 16;
    const int lo0 = r0 * BK;
    const int lo1 = (r0 + 64) * BK;

    auto stage = [&](int k0, int buf) {
        ushort_t* base = lds + buf * 3 * TILE_ELEMS;
        ushort_t* As_h = base;
        ushort_t* Bs_h = base + TILE_ELEMS;
        ushort_t* Bs_l = base + 2 * TILE_ELEMS;
        const size_t go0 = (size_t)(r0 + lrow) * K + k0 + lk;
        const size_t go1 = (size_t)(r0 + 64 + lrow) * K + k0 + lk;
        gload16(Agh + go0, As_h + lo0);
        gload16(Agh + go1, As_h + lo1);
        gload16(Bgh + go0, Bs_h + lo0);
        gload16(Bgh + go1, Bs_h + lo1);
        gload16(Bgl + go0, Bs_l + lo0);
        gload16(Bgl + go1, Bs_l + lo1);
    };

    stage(0, 0);

    const int niter = K / BK;
    for (int it = 0; it < niter; it++) {
        const int cur = it & 1;
        __syncthreads();  // drains vmcnt: tile it visible; buf cur^1 free

        if (it + 1 < niter) stage((it + 1) * BK, cur ^ 1);

        ushort_t* base = lds + cur * 3 * TILE_ELEMS;
        ushort_t* As_h = base;
        ushort_t* Bs_h = base + TILE_ELEMS;
        ushort_t* Bs_l = base + 2 * TILE_ELEMS;

        bf16x8 af_h[4], bf_h[4], bf_l[4];
        #pragma unroll
        for (int i = 0; i < 4; i++) {
            af_h[i] = *(const bf16x8*)&As_h[(wm + i * 16 + lr) * BK + quad * 8];
            bf_h[i] = *(const bf16x8*)&Bs_h[(wn + i * 16 + lr) * BK + quad * 8];
            bf_l[i] = *(const bf16x8*)&Bs_l[(wn + i * 16 + lr) * BK + quad * 8];
        }
        #pragma unroll
        for (int mt = 0; mt < 4; mt++)
            #pragma unroll
            for (int nt = 0; nt < 4; nt++) {
                acc[mt][nt] = __builtin_amdgcn_mfma_f32_16x16x32_bf16(
                    af_h[mt], bf_h[nt], acc[mt][nt], 0, 0, 0);
                acc[mt][nt] = __builtin_amdgcn_mfma_f32_16x16x32_bf16(
                    af_h[mt], bf_l[nt], acc[mt][nt], 0, 0, 0);
            }
    }
}

// ---------------------------------------------------------------------------
// QKV GEMM (2-term) with split-bf16 outputs (epilogue unchanged: q/k/v are
// still stored hi+lo so the attention keeps its verified numerics).
// ---------------------------------------------------------------------------
__global__ __launch_bounds__(256) void gemm_qkv_mfma(
    const ushort_t* __restrict__ xh,
    const ushort_t* __restrict__ Wth, const ushort_t* __restrict__ Wtl,
    const float* __restrict__ bias, const float* __restrict__ freqs,
    const int* __restrict__ input_pos,
    ushort_t* __restrict__ qhg, ushort_t* __restrict__ qlg,
    ushort_t* __restrict__ khg, ushort_t* __restrict__ klg,
    ushort_t* __restrict__ vhg, ushort_t* __restrict__ vlg)
{
    __shared__ ushort_t lds[2 * 3 * TILE_ELEMS];   // 48 KB
    const int t = threadIdx.x;
    const int col0 = blockIdx.x * 128;
    const int row0 = blockIdx.y * 128;

    f32x4 acc[4][4] = {};
    mm_core_2t(xh + (size_t)row0 * D,
               Wth + (size_t)col0 * D, Wtl + (size_t)col0 * D,
               D, lds, t, acc);

    const int lane = t & 63;
    const int quad = lane >> 4;
    const int lr   = lane & 15;
    const int wm = ((t >> 6) & 1) * 64;
    const int wn = ((t >> 6) >> 1) * 64;

    const int which = col0 >> 11;           // 0=q 1=k 2=v
    const int hh = (col0 & 2047) >> 7;

    if (which == 2) {
        ushort_t* vh_b = vhg + (size_t)hh * HD * S;
        ushort_t* vl_b = vlg + (size_t)hh * HD * S;
        #pragma unroll
        for (int nt = 0; nt < 4; nt++) {
            const int d = wn + nt * 16 + lr;
            const float bsc = bias[col0 + d];
            #pragma unroll
            for (int mt = 0; mt < 4; mt++) {
                #pragma unroll
                for (int reg = 0; reg < 4; reg++) {
                    const int m = row0 + wm + mt * 16 + quad * 4 + reg;
                    const float v = acc[mt][nt][reg] + bsc;
                    const ushort_t hv = bf16_rne(v);
                    const ushort_t lv = bf16_rne(v - bf16_f32(hv));
                    const int pos = input_pos[m];
                    vh_b[(size_t)d * S + pos] = hv;
                    vl_b[(size_t)d * S + pos] = lv;
                }
            }
        }
    } else {
        ushort_t* oh_b = ((which == 0) ? qhg : khg) + (size_t)hh * S * HD;
        ushort_t* ol_b = ((which == 0) ? qlg : klg) + (size_t)hh * S * HD;
        #pragma unroll
        for (int nt = 0; nt < 4; nt++) {
            const int d = wn + nt * 16 + lr;
            const float bsc = bias[col0 + d];
            #pragma unroll
            for (int mt = 0; mt < 4; mt++) {
                #pragma unroll
                for (int reg = 0; reg < 4; reg++) {
                    const int m = row0 + wm + mt * 16 + quad * 4 + reg;
                    const float v = acc[mt][nt][reg] + bsc;
                    const float* fc = &freqs[((size_t)m * 64 + (d >> 1)) * 2];
                    const float c = fc[0], s = fc[1];
                    const float p = __shfl_xor(v, 1);
                    const float o = (d & 1) ? (v * c + p * s) : (v * c - p * s);
                    const ushort_t hv = bf16_rne(o);
                    const ushort_t lv = bf16_rne(o - bf16_f32(hv));
                    const int hp = __shfl_xor((int)hv, 1);
                    const int lp = __shfl_xor((int)lv, 1);
                    if (!(d & 1)) {
                        const int srow = (which == 0) ? m : input_pos[m];
                        *(uint_t*)&oh_b[(size_t)srow * HD + d] =
                            (uint_t)hv | ((uint_t)hp << 16);
                        *(uint_t*)&ol_b[(size_t)srow * HD + d] =
                            (uint_t)lv | ((uint_t)lp << 16);
                    }
                }
            }
        }
    }
}

// ---------------------------------------------------------------------------
// MFMA flash attention (R10 verified: dbuf, ones-column l, XCD swizzle).
// R11 change: ctx is stored hi-only (dense is 2-term; ctx-lo never read).
// ---------------------------------------------------------------------------
__global__ __launch_bounds__(256, 2) void attn_mfma_kernel(
    const ushort_t* __restrict__ qhg, const ushort_t* __restrict__ qlg,
    const ushort_t* __restrict__ khg, const ushort_t* __restrict__ klg,
    const ushort_t* __restrict__ vhg, const ushort_t* __restrict__ vlg,
    ushort_t* __restrict__ ctxh)
{
    __shared__ ushort_t Khs[2][4096];   // [buf][ks*1024 + key*32 + d8]
    __shared__ ushort_t Kls[2][4096];
    __shared__ ushort_t Vhs[2][4096];   // [buf][dim*32 + key8]
    __shared__ ushort_t Vls[2][4096];
    __shared__ ushort_t Ps[64 * 32];

    const int bi = blockIdx.x;             // 0..511
    const int h  = (bi & 7) + 8 * ((bi >> 3) & 1);
    const int qi = bi >> 4;                // 0..31
    const int r = (h & 8) ? qi : (31 - qi);
    const int q0 = r * 64;
    const int ntiles = 2 * r + 2;
    const int t = threadIdx.x;
    const int w = t >> 6, lane = t & 63;
    const int lr = lane & 15, quad = lane >> 4;

    const size_t qrow = (size_t)h * S + q0 + w * 16 + lr;
    bf16x8 qf_h[4], qf_l[4];
    #pragma unroll
    for (int ks = 0; ks < 4; ks++) {
        qf_h[ks] = *(const bf16x8*)&qhg[qrow * HD + ks * 32 + quad * 8];
        qf_l[ks] = *(const bf16x8*)&qlg[qrow * HD + ks * 32 + quad * 8];
    }

    const ushort_t* kh_b = khg + (size_t)h * S * HD;
    const ushort_t* kl_b = klg + (size_t)h * S * HD;
    const ushort_t* vh_b = vhg + (size_t)h * HD * S;
    const ushort_t* vl_b = vlg + (size_t)h * HD * S;

    const int keyq = lane >> 2;   // 0..15
    const int sub  = lane & 3;    // 16B chunk index

    auto stage = [&](int kt, int buf) {
        const int k0 = kt * 32;
        #pragma unroll
        for (int hf = 0; hf < 2; hf++) {
            const size_t ksrc = (size_t)(k0 + hf * 16 + keyq) * HD + w * 32 + sub * 8;
            gload16(kh_b + ksrc, &Khs[buf][w * 1024 + hf * 512]);
            gload16(kl_b + ksrc, &Kls[buf][w * 1024 + hf * 512]);
            const int dim = w * 32 + hf * 16 + keyq;
            const size_t vsrc = (size_t)dim * S + k0 + sub * 8;
            gload16(vh_b + vsrc, &Vhs[buf][(w * 32 + hf * 16) * 32]);
            gload16(vl_b + vsrc, &Vls[buf][(w * 32 + hf * 16) * 32]);
        }
    };

    f32x4 O[8] = {};
    f32x4 Ol = {0.f, 0.f, 0.f, 0.f};   // ones-column: per-row softmax denom
    float mrow[4];
    #pragma unroll
    for (int rr = 0; rr < 4; rr++) mrow[rr] = -1e30f;

    bf16x8 onesv;
    #pragma unroll
    for (int i = 0; i < 8; i++) onesv[i] = (short)0x3F80;   // bf16 1.0

    const float kSc = 0.08838834764831845f * 1.4426950408889634f; // scale*log2e

    stage(0, 0);

    for (int kt = 0; kt < ntiles; kt++) {
        const int k0 = kt * 32;
        const int cur = kt & 1;
        __syncthreads();  // drains vmcnt -> tile kt visible; buf cur^1 free

        if (kt + 1 < ntiles) stage(kt + 1, cur ^ 1);

        f32x4 sa[2];
        #pragma unroll
        for (int nt = 0; nt < 2; nt++) {
            f32x4 s = {0.f, 0.f, 0.f, 0.f};
            #pragma unroll
            for (int ks = 0; ks < 4; ks++) {
                bf16x8 kf_h = *(const bf16x8*)&Khs[cur][ks * 1024 + (nt * 16 + lr) * 32 + quad * 8];
                bf16x8 kf_l = *(const bf16x8*)&Kls[cur][ks * 1024 + (nt * 16 + lr) * 32 + quad * 8];
                s = __builtin_amdgcn_mfma_f32_16x16x32_bf16(qf_h[ks], kf_h, s, 0, 0, 0);
                s = __builtin_amdgcn_mfma_f32_16x16x32_bf16(qf_l[ks], kf_h, s, 0, 0, 0);
                s = __builtin_amdgcn_mfma_f32_16x16x32_bf16(qf_h[ks], kf_l, s, 0, 0, 0);
            }
            sa[nt] = s;
        }

        const int rowbase = q0 + w * 16 + quad * 4;
        const bool need_mask = (k0 + 31) > (q0 + w * 16);
        float alpha[4], pv0[4], pv1[4];
        #pragma unroll
        for (int rr = 0; rr < 4; rr++) {
            float z0 = sa[0][rr] * kSc;
            float z1 = sa[1][rr] * kSc;
            if (need_mask) {
                const int rowg = rowbase + rr;
                if (k0 + lr > rowg)      z0 = -1e30f;
                if (k0 + 16 + lr > rowg) z1 = -1e30f;
            }
            float rm = fmaxf(z0, z1);
            #pragma unroll
            for (int off = 1; off < 16; off <<= 1)
                rm = fmaxf(rm, __shfl_xor(rm, off));
            const float nm = fmaxf(mrow[rr], rm);
            alpha[rr] = exp2f(mrow[rr] - nm);
            pv0[rr] = exp2f(z0 - nm);
            pv1[rr] = exp2f(z1 - nm);
            mrow[rr] = nm;
        }

        #pragma unroll
        for (int rr = 0; rr < 4; rr++) {
            const int prow = (w * 16 + quad * 4 + rr) * 32;
            Ps[prow + lr]      = bf16_rne(pv0[rr]);
            Ps[prow + 16 + lr] = bf16_rne(pv1[rr]);
        }
        // no barrier: each wave reads only its own P rows (lgkmcnt orders)

        #pragma unroll
        for (int nt = 0; nt < 8; nt++)
            #pragma unroll
            for (int rr = 0; rr < 4; rr++)
                O[nt][rr] *= alpha[rr];
        #pragma unroll
        for (int rr = 0; rr < 4; rr++)
            Ol[rr] *= alpha[rr];
        const bf16x8 pf = *(const bf16x8*)&Ps[(w * 16 + lr) * 32 + quad * 8];
        #pragma unroll
        for (int nt = 0; nt < 8; nt++) {
            bf16x8 vf_h = *(const bf16x8*)&Vhs[cur][(nt * 16 + lr) * 32 + quad * 8];
            bf16x8 vf_l = *(const bf16x8*)&Vls[cur][(nt * 16 + lr) * 32 + quad * 8];
            O[nt] = __builtin_amdgcn_mfma_f32_16x16x32_bf16(pf, vf_h, O[nt], 0, 0, 0);
            O[nt] = __builtin_amdgcn_mfma_f32_16x16x32_bf16(pf, vf_l, O[nt], 0, 0, 0);
        }
        Ol = __builtin_amdgcn_mfma_f32_16x16x32_bf16(pf, onesv, Ol, 0, 0, 0);
    }

    #pragma unroll
    for (int rr = 0; rr < 4; rr++) {
        const float inv = 1.0f / Ol[rr];
        const int qg = q0 + w * 16 + quad * 4 + rr;
        const size_t roff = (size_t)qg * D + h * HD;
        #pragma unroll
        for (int nt = 0; nt < 8; nt++) {
            const float o = O[nt][rr] * inv;
            const ushort_t hv = bf16_rne(o);
            const int hp = __shfl_xor((int)hv, 1);
            if (!(lr & 1))
                *(uint_t*)&ctxh[roff + nt * 16 + lr] = (uint_t)hv | ((uint_t)hp << 16);
        }
    }
}

// ---------------------------------------------------------------------------
// Dense GEMM (2-term): out = ctx(hi) @ (Wdh + Wdl) + b
// ---------------------------------------------------------------------------
__global__ __launch_bounds__(256) void gemm_dense_mfma(
    const ushort_t* __restrict__ Ah,
    const ushort_t* __restrict__ Wth, const ushort_t* __restrict__ Wtl,
    const float* __restrict__ bias, float* __restrict__ out)
{
    __shared__ ushort_t lds[2 * 3 * TILE_ELEMS];   // 48 KB
    const int t = threadIdx.x;
    const int col0 = blockIdx.x * 128;
    const int row0 = blockIdx.y * 128;

    f32x4 acc[4][4] = {};
    mm_core_2t(Ah + (size_t)row0 * D,
               Wth + (size_t)col0 * D, Wtl + (size_t)col0 * D,
               D, lds, t, acc);

    const int lane = t & 63;
    const int quad = lane >> 4;
    const int lr   = lane & 15;
    const int wm = ((t >> 6) & 1) * 64;
    const int wn = ((t >> 6) >> 1) * 64;

    #pragma unroll
    for (int nt = 0; nt < 4; nt++) {
        const int n = col0 + wn + nt * 16 + lr;
        const float bsc = bias[n];
        #pragma unroll
        for (int mt = 0; mt < 4; mt++) {
            #pragma unroll
            for (int reg = 0; reg < 4; reg++) {
                const int m = row0 + wm + mt * 16 + quad * 4 + reg;
                const float o = acc[mt][nt][reg] + bsc;
                const float po = __shfl_xor(o, 1);
                if (!(n & 1))
                    *(float2*)&out[(size_t)m * D + n] = make_float2(o, po);
            }
        }
    }
}

// ---------------------------------------------------------------------------
// Fallback f32 path (R2, known-good) for small workspace.
// ---------------------------------------------------------------------------
__global__ __launch_bounds__(256) void gemm_qkv_kernel(
    const float* __restrict__ x, const float* __restrict__ W,
    const float* __restrict__ bias, const float* __restrict__ freqs,
    const int* __restrict__ input_pos,
    float* __restrict__ qb, float* __restrict__ kb, float* __restrict__ vb)
{
    __shared__ float As[16][68];
    __shared__ float Bs[16][64];
    const int bx = blockIdx.x;
    const int by = blockIdx.y;
    const int tid = threadIdx.x;
    const int tx = tid & 15, ty = tid >> 4;
    const int row0 = by * 64, col0 = bx * 64;
    const int am = tid >> 2;
    const int ak = (tid & 3) * 4;
    const int bk = tid >> 4;
    const int bn = (tid & 15) * 4;
    float acc[4][4] = {};
    for (int k0 = 0; k0 < D; k0 += 16) {
        float4 av = *(const float4*)&x[(size_t)(row0 + am) * D + k0 + ak];
        float4 bv = *(const float4*)&W[(size_t)(k0 + bk) * N3 + col0 + bn];
        __syncthreads();
        As[ak + 0][am] = av.x; As[ak + 1][am] = av.y;
        As[ak + 2][am] = av.z; As[ak + 3][am] = av.w;
        *(float4*)&Bs[bk][bn] = bv;
        __syncthreads();
        #pragma unroll
        for (int k = 0; k < 16; k++) {
            float4 a4 = *(const float4*)&As[k][ty * 4];
            float4 b4 = *(const float4*)&Bs[k][tx * 4];
            float a[4] = {a4.x, a4.y, a4.z, a4.w};
            float b[4] = {b4.x, b4.y, b4.z, b4.w};
            #pragma unroll
            for (int r = 0; r < 4; r++)
                #pragma unroll
                for (int c = 0; c < 4; c++)
                    acc[r][c] += a[r] * b[c];
        }
    }
    const int j0 = col0 + tx * 4;
    const int which = j0 >> 11;
    const int hh = (j0 & 2047) >> 7;
    const int d0 = j0 & 127;
    const float bv0 = bias[j0 + 0], bv1 = bias[j0 + 1];
    const float bv2 = bias[j0 + 2], bv3 = bias[j0 + 3];
    #pragma unroll
    for (int r = 0; r < 4; r++) {
        const int grow = row0 + ty * 4 + r;
        float v0 = acc[r][0] + bv0, v1 = acc[r][1] + bv1;
        float v2 = acc[r][2] + bv2, v3 = acc[r][3] + bv3;
        if (which == 2) {
            const int pos = input_pos[grow];
            float4 o4 = make_float4(v0, v1, v2, v3);
            *(float4*)&vb[((size_t)hh * S + pos) * HD + d0] = o4;
        } else {
            const float* fc = &freqs[((size_t)grow * 64 + (d0 >> 1)) * 2];
            float c0 = fc[0], s0 = fc[1], c1 = fc[2], s1 = fc[3];
            float o0 = v0 * c0 - v1 * s0, o1 = v1 * c0 + v0 * s0;
            float o2 = v2 * c1 - v3 * s1, o3 = v3 * c1 + v2 * s1;
            float4 o4 = make_float4(o0, o1, o2, o3);
            if (which == 0) {
                *(float4*)&qb[((size_t)hh * S + grow) * HD + d0] = o4;
            } else {
                const int pos = input_pos[grow];
                *(float4*)&kb[((size_t)hh * S + pos) * HD + d0] = o4;
            }
        }
    }
}

#define BQ 64
#define ABK 32
#define QSTR 132
#define KVSTR 132
#define PSTR 68

__global__ __launch_bounds__(256) void attn_kernel(
    const float* __restrict__ qb, const float* __restrict__ kb,
    const float* __restrict__ vb, float* __restrict__ ctx)
{
    __shared__ float Qs[BQ * QSTR];
    __shared__ float KV[ABK * KVSTR];
    __shared__ float Psf[ABK * PSTR];

    const int pa = blockIdx.x;
    const int h  = blockIdx.y;
    const int t  = threadIdx.x;
    const int ty = t >> 4, tx = t & 15;
    const int i0  = ty * 4;
    const int j0  = tx * 2;
    const int dd0 = tx * 8;
    const int lr = t >> 3;
    const int lc = (t & 7) * 4;

    const float* kbase = kb + (size_t)h * S * HD;
    const float* vbase = vb + (size_t)h * S * HD;
    const float kSc = 0.08838834764831845f * 1.4426950408889634f;

    for (int ph = 0; ph < 2; ph++) {
        const int r = (ph == 0) ? pa : 31 - pa;
        const int q0 = r * BQ;
        const int ntiles = 2 * r + 2;

        #pragma unroll
        for (int pp = 0; pp < 2; pp++) {
            const int iq = lr + pp * 32;
            const float* src = qb + ((size_t)h * S + q0 + iq) * HD;
            #pragma unroll
            for (int ch = 0; ch < 4; ch++)
                *(float4*)&Qs[iq * QSTR + lc + ch * 32] =
                    *(const float4*)&src[lc + ch * 32];
        }

        float O[4][8] = {};
        float m[4], l[4];
        #pragma unroll
        for (int rr = 0; rr < 4; rr++) { m[rr] = -1e30f; l[rr] = 0.f; }

        float4 kpref[4];
        #pragma unroll
        for (int ch = 0; ch < 4; ch++)
            kpref[ch] = *(const float4*)&kbase[(size_t)lr * HD + lc + ch * 32];

        __syncthreads();

        for (int kt = 0; kt < ntiles; kt++) {
            const int k0 = kt * ABK;

            #pragma unroll
            for (int ch = 0; ch < 4; ch++)
                *(float4*)&KV[lr * KVSTR + lc + ch * 32] = kpref[ch];
            __syncthreads();

            float4 vpref[4];
            #pragma unroll
            for (int ch = 0; ch < 4; ch++)
                vpref[ch] = *(const float4*)&vbase[(size_t)(k0 + lr) * HD + lc + ch * 32];

            float acc[4][2] = {};
            #pragma unroll 4
            for (int d0 = 0; d0 < HD; d0 += 4) {
                float4 ka = *(const float4*)&KV[(j0 + 0) * KVSTR + d0];
                float4 kb4 = *(const float4*)&KV[(j0 + 1) * KVSTR + d0];
                #pragma unroll
                for (int rr = 0; rr < 4; rr++) {
                    float4 q4 = *(const float4*)&Qs[(i0 + rr) * QSTR + d0];
                    acc[rr][0] += q4.x * ka.x + q4.y * ka.y + q4.z * ka.z + q4.w * ka.w;
                    acc[rr][1] += q4.x * kb4.x + q4.y * kb4.y + q4.z * kb4.z + q4.w * kb4.w;
                }
            }

            const bool need_mask = (k0 + ABK - 1) > q0;
            float p[4][2], alpha[4];
            #pragma unroll
            for (int rr = 0; rr < 4; rr++) {
                float z0 = acc[rr][0] * kSc;
                float z1 = acc[rr][1] * kSc;
                if (need_mask) {
                    if (k0 + j0 + 0 > q0 + i0 + rr) z0 = -1e30f;
                    if (k0 + j0 + 1 > q0 + i0 + rr) z1 = -1e30f;
                }
                float rmax = fmaxf(z0, z1);
                #pragma unroll
                for (int off = 1; off < 16; off <<= 1)
                    rmax = fmaxf(rmax, __shfl_xor(rmax, off, 16));
                const float nm = fmaxf(m[rr], rmax);
                alpha[rr] = exp2f(m[rr] - nm);
                p[rr][0] = exp2f(z0 - nm);
                p[rr][1] = exp2f(z1 - nm);
                float ts = p[rr][0] + p[rr][1];
                #pragma unroll
                for (int off = 1; off < 16; off <<= 1)
                    ts += __shfl_xor(ts, off, 16);
                l[rr] = l[rr] * alpha[rr] + ts;
                m[rr] = nm;
            }
            __syncthreads();

            #pragma unroll
            for (int ch = 0; ch < 4; ch++)
                *(float4*)&KV[lr * KVSTR + lc + ch * 32] = vpref[ch];
            *(float4*)&Psf[(j0 + 0) * PSTR + i0] =
                make_float4(p[0][0], p[1][0], p[2][0], p[3][0]);
            *(float4*)&Psf[(j0 + 1) * PSTR + i0] =
                make_float4(p[0][1], p[1][1], p[2][1], p[3][1]);
            if (kt + 1 < ntiles) {
                #pragma unroll
                for (int ch = 0; ch < 4; ch++)
                    kpref[ch] = *(const float4*)&kbase[(size_t)(k0 + ABK + lr) * HD + lc + ch * 32];
            }
            __syncthreads();

            #pragma unroll
            for (int rr = 0; rr < 4; rr++)
                #pragma unroll
                for (int c = 0; c < 8; c++)
                    O[rr][c] *= alpha[rr];
            #pragma unroll 4
            for (int j = 0; j < ABK; j++) {
                float4 pj = *(const float4*)&Psf[j * PSTR + i0];
                float4 v0 = *(const float4*)&KV[j * KVSTR + dd0];
                float4 v1 = *(const float4*)&KV[j * KVSTR + dd0 + 4];
                const float pr[4] = {pj.x, pj.y, pj.z, pj.w};
                const float vv[8] = {v0.x, v0.y, v0.z, v0.w, v1.x, v1.y, v1.z, v1.w};
                #pragma unroll
                for (int rr = 0; rr < 4; rr++)
                    #pragma unroll
                    for (int c = 0; c < 8; c++)
                        O[rr][c] += pr[rr] * vv[c];
            }
            __syncthreads();
        }

        #pragma unroll
        for (int rr = 0; rr < 4; rr++) {
            const float inv = 1.0f / l[rr];
            const int qg = q0 + i0 + rr;
            float4 o0 = make_float4(O[rr][0] * inv, O[rr][1] * inv,
                                    O[rr][2] * inv, O[rr][3] * inv);
            float4 o1 = make_float4(O[rr][4] * inv, O[rr][5] * inv,
                                    O[rr][6] * inv, O[rr][7] * inv);
            float* dst = &ctx[((size_t)qg * H + h) * HD + dd0];
            *(float4*)&dst[0] = o0;
            *(float4*)&dst[4] = o1;
        }
        __syncthreads();
    }
}

__global__ __launch_bounds__(256) void gemm_dense_kernel(
    const float* __restrict__ A, const float* __restrict__ W,
    const float* __restrict__ bias, float* __restrict__ out)
{
    __shared__ float As[16][68];
    __shared__ float Bs[16][64];
    const int bx = blockIdx.x;
    const int by = blockIdx.y;
    const int tid = threadIdx.x;
    const int tx = tid & 15, ty = tid >> 4;
    const int row0 = by * 64, col0 = bx * 64;
    const int am = tid >> 2;
    const int ak = (tid & 3) * 4;
    const int bk = tid >> 4;
    const int bn = (tid & 15) * 4;
    float acc[4][4] = {};
    for (int k0 = 0; k0 < D; k0 += 16) {
        float4 av = *(const float4*)&A[(size_t)(row0 + am) * D + k0 + ak];
        float4 bv = *(const float4*)&W[(size_t)(k0 + bk) * D + col0 + bn];
        __syncthreads();
        As[ak + 0][am] = av.x; As[ak + 1][am] = av.y;
        As[ak + 2][am] = av.z; As[ak + 3][am] = av.w;
        *(float4*)&Bs[bk][bn] = bv;
        __syncthreads();
        #pragma unroll
        for (int k = 0; k < 16; k++) {
            float4 a4 = *(const float4*)&As[k][ty * 4];
            float4 b4 = *(const float4*)&Bs[k][tx * 4];
            float a[4] = {a4.x, a4.y, a4.z, a4.w};
            float b[4] = {b4.x, b4.y, b4.z, b4.w};
            #pragma unroll
            for (int r = 0; r < 4; r++)
                #pragma unroll
                for (int c = 0; c < 4; c++)
                    acc[r][c] += a[r] * b[c];
        }
    }
    const int j0 = col0 + tx * 4;
    const float bv0 = bias[j0 + 0], bv1 = bias[j0 + 1];
    const float bv2 = bias[j0 + 2], bv3 = bias[j0 + 3];
    #pragma unroll
    for (int r = 0; r < 4; r++) {
        const int grow = row0 + ty * 4 + r;
        float4 o4 = make_float4(acc[r][0] + bv0, acc[r][1] + bv1,
                                acc[r][2] + bv2, acc[r][3] + bv3);
        *(float4*)&out[(size_t)grow * D + j0] = o4;
    }
}

extern "C" void kernel_launch(void* const* d_in, const int* in_sizes, int n_in,
                              void* d_out, int out_size, void* d_ws, size_t ws_size,
                              hipStream_t stream) {
    const float* x      = (const float*)d_in[0];
    const float* freqs  = (const float*)d_in[1];
    const int*   pos    = (const int*)d_in[2];
    const float* Wqkv   = (const float*)d_in[3];
    const float* bqkv   = (const float*)d_in[4];
    const float* Wdense = (const float*)d_in[5];
    const float* bdense = (const float*)d_in[6];
    float* out = (float*)d_out;

    const size_t nSD = (size_t)S * D;   // 4 Mi elems
    const size_t nW1 = (size_t)D * N3;  // 12 Mi elems

    // ws layout kept from R9/R10 (some slots now unused): 144 MiB check
    const size_t needed = (12 * nSD + 2 * nW1) * sizeof(ushort_t);

    if (ws_size >= needed) {
        ushort_t* qh   = (ushort_t*)d_ws;
        ushort_t* ql   = qh + nSD;
        ushort_t* kh   = ql + nSD;
        ushort_t* kl   = kh + nSD;
        ushort_t* vh   = kl + nSD;
        ushort_t* vl   = vh + nSD;
        ushort_t* ctxh = vl + nSD;
        ushort_t* xh   = ctxh + 2 * nSD;   // (old ctxl slot unused)
        ushort_t* Wth  = xh + 2 * nSD;     // (old xl slot unused)
        ushort_t* Wtl  = Wth + nW1;
        ushort_t* Wdth = Wtl + nW1;
        ushort_t* Wdtl = Wdth + nSD;

        convert_hi_kernel<<<nSD / 4 / 256, 256, 0, stream>>>(x, xh);
        dim3 gt1(D / 32, N3 / 32);
        convert_split_t_kernel<<<gt1, 256, 0, stream>>>(Wqkv, Wth, Wtl, D, N3);
        dim3 gt2(D / 32, D / 32);
        convert_split_t_kernel<<<gt2, 256, 0, stream>>>(Wdense, Wdth, Wdtl, D, D);

        dim3 g1(N3 / 128, S / 128);
        gemm_qkv_mfma<<<g1, 256, 0, stream>>>(xh, Wth, Wtl, bqkv, freqs,
                                              pos, qh, ql, kh, kl, vh, vl);
        attn_mfma_kernel<<<512, 256, 0, stream>>>(qh, ql, kh, kl, vh, vl, ctxh);
        dim3 g3(D / 128, S / 128);
        gemm_dense_mfma<<<g3, 256, 0, stream>>>(ctxh, Wdth, Wdtl, bdense, out);
    } else {
        // fallback: R2 f32 path (needs only 64 MiB)
        float* qb  = (float*)d_ws;
        float* kb  = qb + (size_t)H * S * HD;
        float* vb  = kb + (size_t)H * S * HD;
        float* ctx = vb + (size_t)H * S * HD;
        dim3 g1(N3 / 64, S / 64);
        gemm_qkv_kernel<<<g1, 256, 0, stream>>>(x, Wqkv, bqkv, freqs, pos, qb, kb, vb);
        dim3 g2(16, H);
        attn_kernel<<<g2, 256, 0, stream>>>(qb, kb, vb, ctx);
        dim3 g3(D / 64, S / 64);
        gemm_dense_kernel<<<g3, 256, 0, stream>>>(ctx, Wdense, bdense, out);
    }
}

// Round 12
// 463.094 us; speedup vs baseline: 1.3803x; 1.0690x over previous
//
#include <hip/hip_runtime.h>

#define S 2048
#define D 2048
#define H 16
#define HD 128
#define N3 6144  // 3*D

typedef __attribute__((ext_vector_type(8))) short bf16x8;
typedef __attribute__((ext_vector_type(4))) float f32x4;
typedef unsigned short ushort_t;
typedef unsigned int uint_t;

// ---------------------------------------------------------------------------
// bf16 split helpers (round-to-nearest-even)
// ---------------------------------------------------------------------------
__device__ __forceinline__ ushort_t bf16_rne(float f) {
    uint_t u = __float_as_uint(f);
    u += 0x7fffu + ((u >> 16) & 1u);
    return (ushort_t)(u >> 16);
}
__device__ __forceinline__ float bf16_f32(ushort_t h) {
    return __uint_as_float(((uint_t)h) << 16);
}

// f32 row-major -> hi bf16 only (activations)
__global__ __launch_bounds__(256) void convert_hi_kernel(
    const float* __restrict__ in, ushort_t* __restrict__ hi)
{
    const int i = blockIdx.x * 256 + threadIdx.x;  // per float4
    float4 v = ((const float4*)in)[i];
    ((ushort4*)hi)[i] = make_ushort4(bf16_rne(v.x), bf16_rne(v.y),
                                     bf16_rne(v.z), bf16_rne(v.w));
}

// W [K][N] f32 -> Wt hi/lo [N][K] bf16 (transpose + split), 32x32 tiles.
__global__ __launch_bounds__(256) void convert_split_t_kernel(
    const float* __restrict__ in, ushort_t* __restrict__ hi,
    ushort_t* __restrict__ lo, int Kdim, int Ndim)
{
    __shared__ float tile[32][33];
    const int k0 = blockIdx.x * 32, n0 = blockIdx.y * 32;
    const int tx = threadIdx.x & 31, ty = threadIdx.x >> 5;  // ty 0..7
    #pragma unroll
    for (int r = 0; r < 4; r++)
        tile[ty + r * 8][tx] = in[(size_t)(k0 + ty + r * 8) * Ndim + n0 + tx];
    __syncthreads();
    const int n  = threadIdx.x >> 3;        // 0..31 local col
    const int kc = (threadIdx.x & 7) * 4;   // 0..28 local k chunk
    const float v0 = tile[kc + 0][n], v1 = tile[kc + 1][n];
    const float v2 = tile[kc + 2][n], v3 = tile[kc + 3][n];
    const ushort_t h0 = bf16_rne(v0), h1 = bf16_rne(v1);
    const ushort_t h2 = bf16_rne(v2), h3 = bf16_rne(v3);
    const size_t off = (size_t)(n0 + n) * Kdim + k0 + kc;
    *(ushort4*)&hi[off] = make_ushort4(h0, h1, h2, h3);
    *(ushort4*)&lo[off] = make_ushort4(bf16_rne(v0 - bf16_f32(h0)),
                                       bf16_rne(v1 - bf16_f32(h1)),
                                       bf16_rne(v2 - bf16_f32(h2)),
                                       bf16_rne(v3 - bf16_f32(h3)));
}

// ---------------------------------------------------------------------------
// async global->LDS, 16 B per lane, wave-uniform LDS base (HW adds lane*16).
// ---------------------------------------------------------------------------
__device__ __forceinline__ void gload16(const ushort_t* g, ushort_t* l) {
    __builtin_amdgcn_global_load_lds(
        (const __attribute__((address_space(1))) unsigned int*)g,
        (__attribute__((address_space(3))) unsigned int*)l, 16, 0, 0);
}

// ---------------------------------------------------------------------------
// 2-term split GEMM core (R11, verified 178 us qkv): C = Ah*(Bh + Bl).
// BK=32, 16x16x32, dbuf 48 KB. (R8's BK=16 interleave regressed — no re-try.)
// ---------------------------------------------------------------------------
#define BK 32
#define TILE_ELEMS (128 * BK)

__device__ __forceinline__ void mm_core_2t(
    const ushort_t* __restrict__ Agh,
    const ushort_t* __restrict__ Bgh, const ushort_t* __restrict__ Bgl,
    const int K, ushort_t* lds, const int t, f32x4 (&acc)[4][4])
{
    const int lane = t & 63;
    const int wv   = t >> 6;
    const int lrow = lane >> 2;
    const int lk   = (lane & 3) * 8;
    const int quad = lane >> 4;
    const int lr   = lane & 15;
    const int wm   = (wv & 1) * 64;
    const int wn   = (wv >> 1) * 64;

    const int r0  = wv * 16;
    const int lo0 = r0 * BK;
    const int lo1 = (r0 + 64) * BK;

    auto stage = [&](int k0, int buf) {
        ushort_t* base = lds + buf * 3 * TILE_ELEMS;
        ushort_t* As_h = base;
        ushort_t* Bs_h = base + TILE_ELEMS;
        ushort_t* Bs_l = base + 2 * TILE_ELEMS;
        const size_t go0 = (size_t)(r0 + lrow) * K + k0 + lk;
        const size_t go1 = (size_t)(r0 + 64 + lrow) * K + k0 + lk;
        gload16(Agh + go0, As_h + lo0);
        gload16(Agh + go1, As_h + lo1);
        gload16(Bgh + go0, Bs_h + lo0);
        gload16(Bgh + go1, Bs_h + lo1);
        gload16(Bgl + go0, Bs_l + lo0);
        gload16(Bgl + go1, Bs_l + lo1);
    };

    stage(0, 0);

    const int niter = K / BK;
    for (int it = 0; it < niter; it++) {
        const int cur = it & 1;
        __syncthreads();  // drains vmcnt: tile it visible; buf cur^1 free

        if (it + 1 < niter) stage((it + 1) * BK, cur ^ 1);

        ushort_t* base = lds + cur * 3 * TILE_ELEMS;
        ushort_t* As_h = base;
        ushort_t* Bs_h = base + TILE_ELEMS;
        ushort_t* Bs_l = base + 2 * TILE_ELEMS;

        bf16x8 af_h[4], bf_h[4], bf_l[4];
        #pragma unroll
        for (int i = 0; i < 4; i++) {
            af_h[i] = *(const bf16x8*)&As_h[(wm + i * 16 + lr) * BK + quad * 8];
            bf_h[i] = *(const bf16x8*)&Bs_h[(wn + i * 16 + lr) * BK + quad * 8];
            bf_l[i] = *(const bf16x8*)&Bs_l[(wn + i * 16 + lr) * BK + quad * 8];
        }
        #pragma unroll
        for (int mt = 0; mt < 4; mt++)
            #pragma unroll
            for (int nt = 0; nt < 4; nt++) {
                acc[mt][nt] = __builtin_amdgcn_mfma_f32_16x16x32_bf16(
                    af_h[mt], bf_h[nt], acc[mt][nt], 0, 0, 0);
                acc[mt][nt] = __builtin_amdgcn_mfma_f32_16x16x32_bf16(
                    af_h[mt], bf_l[nt], acc[mt][nt], 0, 0, 0);
            }
    }
}

// ---------------------------------------------------------------------------
// QKV GEMM (2-term). R12: q/k stored HI-ONLY (attention QK is 1-term now);
// v stays hi+lo (PV keeps 2-term precision).
// ---------------------------------------------------------------------------
__global__ __launch_bounds__(256) void gemm_qkv_mfma(
    const ushort_t* __restrict__ xh,
    const ushort_t* __restrict__ Wth, const ushort_t* __restrict__ Wtl,
    const float* __restrict__ bias, const float* __restrict__ freqs,
    const int* __restrict__ input_pos,
    ushort_t* __restrict__ qhg, ushort_t* __restrict__ khg,
    ushort_t* __restrict__ vhg, ushort_t* __restrict__ vlg)
{
    __shared__ ushort_t lds[2 * 3 * TILE_ELEMS];   // 48 KB
    const int t = threadIdx.x;
    const int col0 = blockIdx.x * 128;
    const int row0 = blockIdx.y * 128;

    f32x4 acc[4][4] = {};
    mm_core_2t(xh + (size_t)row0 * D,
               Wth + (size_t)col0 * D, Wtl + (size_t)col0 * D,
               D, lds, t, acc);

    const int lane = t & 63;
    const int quad = lane >> 4;
    const int lr   = lane & 15;
    const int wm = ((t >> 6) & 1) * 64;
    const int wn = ((t >> 6) >> 1) * 64;

    const int which = col0 >> 11;           // 0=q 1=k 2=v
    const int hh = (col0 & 2047) >> 7;

    if (which == 2) {
        ushort_t* vh_b = vhg + (size_t)hh * HD * S;
        ushort_t* vl_b = vlg + (size_t)hh * HD * S;
        #pragma unroll
        for (int nt = 0; nt < 4; nt++) {
            const int d = wn + nt * 16 + lr;
            const float bsc = bias[col0 + d];
            #pragma unroll
            for (int mt = 0; mt < 4; mt++) {
                #pragma unroll
                for (int reg = 0; reg < 4; reg++) {
                    const int m = row0 + wm + mt * 16 + quad * 4 + reg;
                    const float v = acc[mt][nt][reg] + bsc;
                    const ushort_t hv = bf16_rne(v);
                    const ushort_t lv = bf16_rne(v - bf16_f32(hv));
                    const int pos = input_pos[m];
                    vh_b[(size_t)d * S + pos] = hv;
                    vl_b[(size_t)d * S + pos] = lv;
                }
            }
        }
    } else {
        ushort_t* oh_b = ((which == 0) ? qhg : khg) + (size_t)hh * S * HD;
        #pragma unroll
        for (int nt = 0; nt < 4; nt++) {
            const int d = wn + nt * 16 + lr;
            const float bsc = bias[col0 + d];
            #pragma unroll
            for (int mt = 0; mt < 4; mt++) {
                #pragma unroll
                for (int reg = 0; reg < 4; reg++) {
                    const int m = row0 + wm + mt * 16 + quad * 4 + reg;
                    const float v = acc[mt][nt][reg] + bsc;
                    const float* fc = &freqs[((size_t)m * 64 + (d >> 1)) * 2];
                    const float c = fc[0], s = fc[1];
                    const float p = __shfl_xor(v, 1);
                    const float o = (d & 1) ? (v * c + p * s) : (v * c - p * s);
                    const ushort_t hv = bf16_rne(o);
                    const int hp = __shfl_xor((int)hv, 1);
                    if (!(d & 1)) {
                        const int srow = (which == 0) ? m : input_pos[m];
                        *(uint_t*)&oh_b[(size_t)srow * HD + d] =
                            (uint_t)hv | ((uint_t)hp << 16);
                    }
                }
            }
        }
    }
}

// ---------------------------------------------------------------------------
// MFMA flash attention, R12: SPLIT-K x2 (flash-decoding). 1024 blocks:
// bi -> h = (bi&7)+8*((bi>>3)&1) (XCD locality), half=(bi>>4)&1, qi=bi>>5,
// r = (h&8)? qi : 31-qi (pairwise CU balance). Each block does tiles
// [half*(r+1), (half+1)*(r+1)) -> max 32 serial tiles (was 64: the lone
// r=31 block set the wall). Partial (unnormalized O, m, l) -> ws; exact
// online-softmax merge in attn_combine_kernel. QK is 1-term (qh*kh): the
// dropped split terms are ~7e-4 in exp2-units, far below the 2e-3
// P-rounding that dominates absmax. PV stays 2-term. LDS 52 KB.
// ---------------------------------------------------------------------------
__global__ __launch_bounds__(256, 2) void attn_mfma_kernel(
    const ushort_t* __restrict__ qhg, const ushort_t* __restrict__ khg,
    const ushort_t* __restrict__ vhg, const ushort_t* __restrict__ vlg,
    float* __restrict__ Opart, float* __restrict__ MLpart)
{
    __shared__ ushort_t Khs[2][4096];   // [buf][hf*512.. key*32 + d8] per wave chunk
    __shared__ ushort_t Vhs[2][4096];   // [buf][dim*32 + key8]
    __shared__ ushort_t Vls[2][4096];
    __shared__ ushort_t Ps[64 * 32];

    const int bi   = blockIdx.x;           // 0..1023
    const int h    = (bi & 7) + 8 * ((bi >> 3) & 1);
    const int half = (bi >> 4) & 1;
    const int qi   = bi >> 5;              // 0..31
    const int r = (h & 8) ? qi : (31 - qi);
    const int q0 = r * 64;
    const int nhalf = r + 1;
    const int kt0 = half * nhalf;
    const int kt1 = kt0 + nhalf;
    const int t = threadIdx.x;
    const int w = t >> 6, lane = t & 63;
    const int lr = lane & 15, quad = lane >> 4;

    const size_t qrow = (size_t)h * S + q0 + w * 16 + lr;
    bf16x8 qf_h[4];
    #pragma unroll
    for (int ks = 0; ks < 4; ks++)
        qf_h[ks] = *(const bf16x8*)&qhg[qrow * HD + ks * 32 + quad * 8];

    const ushort_t* kh_b = khg + (size_t)h * S * HD;
    const ushort_t* vh_b = vhg + (size_t)h * HD * S;
    const ushort_t* vl_b = vlg + (size_t)h * HD * S;

    const int keyq = lane >> 2;   // 0..15
    const int sub  = lane & 3;    // 16B chunk index

    auto stage = [&](int kt, int buf) {
        const int k0 = kt * 32;
        #pragma unroll
        for (int hf = 0; hf < 2; hf++) {
            const size_t ksrc = (size_t)(k0 + hf * 16 + keyq) * HD + w * 32 + sub * 8;
            gload16(kh_b + ksrc, &Khs[buf][w * 1024 + hf * 512]);
            const int dim = w * 32 + hf * 16 + keyq;
            const size_t vsrc = (size_t)dim * S + k0 + sub * 8;
            gload16(vh_b + vsrc, &Vhs[buf][(w * 32 + hf * 16) * 32]);
            gload16(vl_b + vsrc, &Vls[buf][(w * 32 + hf * 16) * 32]);
        }
    };

    f32x4 O[8] = {};
    f32x4 Ol = {0.f, 0.f, 0.f, 0.f};   // ones-column: per-row denom (unnorm)
    float mrow[4];
    #pragma unroll
    for (int rr = 0; rr < 4; rr++) mrow[rr] = -1e30f;

    bf16x8 onesv;
    #pragma unroll
    for (int i = 0; i < 8; i++) onesv[i] = (short)0x3F80;   // bf16 1.0

    const float kSc = 0.08838834764831845f * 1.4426950408889634f; // scale*log2e

    stage(kt0, 0);

    for (int kt = kt0; kt < kt1; kt++) {
        const int k0 = kt * 32;
        const int cur = (kt - kt0) & 1;
        __syncthreads();  // drains vmcnt -> tile kt visible; buf cur^1 free

        if (kt + 1 < kt1) stage(kt + 1, cur ^ 1);

        // ---- scores: 1-term qh*kh
        f32x4 sa[2];
        #pragma unroll
        for (int nt = 0; nt < 2; nt++) {
            f32x4 s = {0.f, 0.f, 0.f, 0.f};
            #pragma unroll
            for (int ks = 0; ks < 4; ks++) {
                bf16x8 kf_h = *(const bf16x8*)&Khs[cur][ks * 1024 + (nt * 16 + lr) * 32 + quad * 8];
                s = __builtin_amdgcn_mfma_f32_16x16x32_bf16(qf_h[ks], kf_h, s, 0, 0, 0);
            }
            sa[nt] = s;
        }

        const int rowbase = q0 + w * 16 + quad * 4;
        const bool need_mask = (k0 + 31) > (q0 + w * 16);
        float alpha[4], pv0[4], pv1[4];
        #pragma unroll
        for (int rr = 0; rr < 4; rr++) {
            float z0 = sa[0][rr] * kSc;
            float z1 = sa[1][rr] * kSc;
            if (need_mask) {
                const int rowg = rowbase + rr;
                if (k0 + lr > rowg)      z0 = -1e30f;
                if (k0 + 16 + lr > rowg) z1 = -1e30f;
            }
            float rm = fmaxf(z0, z1);
            #pragma unroll
            for (int off = 1; off < 16; off <<= 1)
                rm = fmaxf(rm, __shfl_xor(rm, off));
            const float nm = fmaxf(mrow[rr], rm);
            alpha[rr] = exp2f(mrow[rr] - nm);
            pv0[rr] = exp2f(z0 - nm);
            pv1[rr] = exp2f(z1 - nm);
            mrow[rr] = nm;
        }

        #pragma unroll
        for (int rr = 0; rr < 4; rr++) {
            const int prow = (w * 16 + quad * 4 + rr) * 32;
            Ps[prow + lr]      = bf16_rne(pv0[rr]);
            Ps[prow + 16 + lr] = bf16_rne(pv1[rr]);
        }
        // no barrier: each wave reads only its own P rows (lgkmcnt orders)

        #pragma unroll
        for (int nt = 0; nt < 8; nt++)
            #pragma unroll
            for (int rr = 0; rr < 4; rr++)
                O[nt][rr] *= alpha[rr];
        #pragma unroll
        for (int rr = 0; rr < 4; rr++)
            Ol[rr] *= alpha[rr];
        const bf16x8 pf = *(const bf16x8*)&Ps[(w * 16 + lr) * 32 + quad * 8];
        #pragma unroll
        for (int nt = 0; nt < 8; nt++) {
            bf16x8 vf_h = *(const bf16x8*)&Vhs[cur][(nt * 16 + lr) * 32 + quad * 8];
            bf16x8 vf_l = *(const bf16x8*)&Vls[cur][(nt * 16 + lr) * 32 + quad * 8];
            O[nt] = __builtin_amdgcn_mfma_f32_16x16x32_bf16(pf, vf_h, O[nt], 0, 0, 0);
            O[nt] = __builtin_amdgcn_mfma_f32_16x16x32_bf16(pf, vf_l, O[nt], 0, 0, 0);
        }
        Ol = __builtin_amdgcn_mfma_f32_16x16x32_bf16(pf, onesv, Ol, 0, 0, 0);
    }

    // ---- store unnormalized partial O + (m, l) for the combine pass
    float* Ob = Opart + (size_t)bi * 64 * 128;
    #pragma unroll
    for (int rr = 0; rr < 4; rr++) {
        const int row = w * 16 + quad * 4 + rr;
        #pragma unroll
        for (int nt = 0; nt < 8; nt++)
            Ob[(size_t)row * 128 + nt * 16 + lr] = O[nt][rr];
        if (lr == 0) {
            MLpart[(size_t)bi * 128 + row * 2 + 0] = mrow[rr];
            MLpart[(size_t)bi * 128 + row * 2 + 1] = Ol[rr];
        }
    }
}

// ---------------------------------------------------------------------------
// Exact online-softmax merge of the two split-K halves -> ctxh (bf16).
// ---------------------------------------------------------------------------
__global__ __launch_bounds__(128) void attn_combine_kernel(
    const float* __restrict__ Opart, const float* __restrict__ MLpart,
    ushort_t* __restrict__ ctxh)
{
    const int qt = blockIdx.x;   // 0..31 (qi in attn kernel)
    const int h  = blockIdx.y;   // 0..15
    const int t  = threadIdx.x;  // 0..127
    const int b0 = h | (qt << 5);          // half 0
    const int b1 = b0 | (1 << 4);          // half 1
    const int r = (h & 8) ? qt : (31 - qt);
    const int q0 = r * 64;

    __shared__ float sc[64][2];
    if (t < 64) {
        const float m0 = MLpart[(size_t)b0 * 128 + t * 2 + 0];
        const float l0 = MLpart[(size_t)b0 * 128 + t * 2 + 1];
        const float m1 = MLpart[(size_t)b1 * 128 + t * 2 + 0];
        const float l1 = MLpart[(size_t)b1 * 128 + t * 2 + 1];
        const float m = fmaxf(m0, m1);
        const float a0 = exp2f(m0 - m), a1 = exp2f(m1 - m);
        const float inv = 1.0f / (l0 * a0 + l1 * a1);
        sc[t][0] = a0 * inv;
        sc[t][1] = a1 * inv;
    }
    __syncthreads();

    const float* O0 = Opart + (size_t)b0 * 64 * 128;
    const float* O1 = Opart + (size_t)b1 * 64 * 128;
    for (int row = 0; row < 64; row++) {
        const float o = O0[(size_t)row * 128 + t] * sc[row][0] +
                        O1[(size_t)row * 128 + t] * sc[row][1];
        ctxh[(size_t)(q0 + row) * D + h * HD + t] = bf16_rne(o);
    }
}

// ---------------------------------------------------------------------------
// Dense GEMM (2-term): out = ctx(hi) @ (Wdh + Wdl) + b
// ---------------------------------------------------------------------------
__global__ __launch_bounds__(256) void gemm_dense_mfma(
    const ushort_t* __restrict__ Ah,
    const ushort_t* __restrict__ Wth, const ushort_t* __restrict__ Wtl,
    const float* __restrict__ bias, float* __restrict__ out)
{
    __shared__ ushort_t lds[2 * 3 * TILE_ELEMS];   // 48 KB
    const int t = threadIdx.x;
    const int col0 = blockIdx.x * 128;
    const int row0 = blockIdx.y * 128;

    f32x4 acc[4][4] = {};
    mm_core_2t(Ah + (size_t)row0 * D,
               Wth + (size_t)col0 * D, Wtl + (size_t)col0 * D,
               D, lds, t, acc);

    const int lane = t & 63;
    const int quad = lane >> 4;
    const int lr   = lane & 15;
    const int wm = ((t >> 6) & 1) * 64;
    const int wn = ((t >> 6) >> 1) * 64;

    #pragma unroll
    for (int nt = 0; nt < 4; nt++) {
        const int n = col0 + wn + nt * 16 + lr;
        const float bsc = bias[n];
        #pragma unroll
        for (int mt = 0; mt < 4; mt++) {
            #pragma unroll
            for (int reg = 0; reg < 4; reg++) {
                const int m = row0 + wm + mt * 16 + quad * 4 + reg;
                const float o = acc[mt][nt][reg] + bsc;
                const float po = __shfl_xor(o, 1);
                if (!(n & 1))
                    *(float2*)&out[(size_t)m * D + n] = make_float2(o, po);
            }
        }
    }
}

// ---------------------------------------------------------------------------
// Fallback f32 path (R2, known-good) for small workspace.
// ---------------------------------------------------------------------------
__global__ __launch_bounds__(256) void gemm_qkv_kernel(
    const float* __restrict__ x, const float* __restrict__ W,
    const float* __restrict__ bias, const float* __restrict__ freqs,
    const int* __restrict__ input_pos,
    float* __restrict__ qb, float* __restrict__ kb, float* __restrict__ vb)
{
    __shared__ float As[16][68];
    __shared__ float Bs[16][64];
    const int bx = blockIdx.x;
    const int by = blockIdx.y;
    const int tid = threadIdx.x;
    const int tx = tid & 15, ty = tid >> 4;
    const int row0 = by * 64, col0 = bx * 64;
    const int am = tid >> 2;
    const int ak = (tid & 3) * 4;
    const int bk = tid >> 4;
    const int bn = (tid & 15) * 4;
    float acc[4][4] = {};
    for (int k0 = 0; k0 < D; k0 += 16) {
        float4 av = *(const float4*)&x[(size_t)(row0 + am) * D + k0 + ak];
        float4 bv = *(const float4*)&W[(size_t)(k0 + bk) * N3 + col0 + bn];
        __syncthreads();
        As[ak + 0][am] = av.x; As[ak + 1][am] = av.y;
        As[ak + 2][am] = av.z; As[ak + 3][am] = av.w;
        *(float4*)&Bs[bk][bn] = bv;
        __syncthreads();
        #pragma unroll
        for (int k = 0; k < 16; k++) {
            float4 a4 = *(const float4*)&As[k][ty * 4];
            float4 b4 = *(const float4*)&Bs[k][tx * 4];
            float a[4] = {a4.x, a4.y, a4.z, a4.w};
            float b[4] = {b4.x, b4.y, b4.z, b4.w};
            #pragma unroll
            for (int r = 0; r < 4; r++)
                #pragma unroll
                for (int c = 0; c < 4; c++)
                    acc[r][c] += a[r] * b[c];
        }
    }
    const int j0 = col0 + tx * 4;
    const int which = j0 >> 11;
    const int hh = (j0 & 2047) >> 7;
    const int d0 = j0 & 127;
    const float bv0 = bias[j0 + 0], bv1 = bias[j0 + 1];
    const float bv2 = bias[j0 + 2], bv3 = bias[j0 + 3];
    #pragma unroll
    for (int r = 0; r < 4; r++) {
        const int grow = row0 + ty * 4 + r;
        float v0 = acc[r][0] + bv0, v1 = acc[r][1] + bv1;
        float v2 = acc[r][2] + bv2, v3 = acc[r][3] + bv3;
        if (which == 2) {
            const int pos = input_pos[grow];
            float4 o4 = make_float4(v0, v1, v2, v3);
            *(float4*)&vb[((size_t)hh * S + pos) * HD + d0] = o4;
        } else {
            const float* fc = &freqs[((size_t)grow * 64 + (d0 >> 1)) * 2];
            float c0 = fc[0], s0 = fc[1], c1 = fc[2], s1 = fc[3];
            float o0 = v0 * c0 - v1 * s0, o1 = v1 * c0 + v0 * s0;
            float o2 = v2 * c1 - v3 * s1, o3 = v3 * c1 + v2 * s1;
            float4 o4 = make_float4(o0, o1, o2, o3);
            if (which == 0) {
                *(float4*)&qb[((size_t)hh * S + grow) * HD + d0] = o4;
            } else {
                const int pos = input_pos[grow];
                *(float4*)&kb[((size_t)hh * S + pos) * HD + d0] = o4;
            }
        }
    }
}

#define BQ 64
#define ABK 32
#define QSTR 132
#define KVSTR 132
#define PSTR 68

__global__ __launch_bounds__(256) void attn_kernel(
    const float* __restrict__ qb, const float* __restrict__ kb,
    const float* __restrict__ vb, float* __restrict__ ctx)
{
    __shared__ float Qs[BQ * QSTR];
    __shared__ float KV[ABK * KVSTR];
    __shared__ float Psf[ABK * PSTR];

    const int pa = blockIdx.x;
    const int h  = blockIdx.y;
    const int t  = threadIdx.x;
    const int ty = t >> 4, tx = t & 15;
    const int i0  = ty * 4;
    const int j0  = tx * 2;
    const int dd0 = tx * 8;
    const int lr = t >> 3;
    const int lc = (t & 7) * 4;

    const float* kbase = kb + (size_t)h * S * HD;
    const float* vbase = vb + (size_t)h * S * HD;
    const float kSc = 0.08838834764831845f * 1.4426950408889634f;

    for (int ph = 0; ph < 2; ph++) {
        const int r = (ph == 0) ? pa : 31 - pa;
        const int q0 = r * BQ;
        const int ntiles = 2 * r + 2;

        #pragma unroll
        for (int pp = 0; pp < 2; pp++) {
            const int iq = lr + pp * 32;
            const float* src = qb + ((size_t)h * S + q0 + iq) * HD;
            #pragma unroll
            for (int ch = 0; ch < 4; ch++)
                *(float4*)&Qs[iq * QSTR + lc + ch * 32] =
                    *(const float4*)&src[lc + ch * 32];
        }

        float O[4][8] = {};
        float m[4], l[4];
        #pragma unroll
        for (int rr = 0; rr < 4; rr++) { m[rr] = -1e30f; l[rr] = 0.f; }

        float4 kpref[4];
        #pragma unroll
        for (int ch = 0; ch < 4; ch++)
            kpref[ch] = *(const float4*)&kbase[(size_t)lr * HD + lc + ch * 32];

        __syncthreads();

        for (int kt = 0; kt < ntiles; kt++) {
            const int k0 = kt * ABK;

            #pragma unroll
            for (int ch = 0; ch < 4; ch++)
                *(float4*)&KV[lr * KVSTR + lc + ch * 32] = kpref[ch];
            __syncthreads();

            float4 vpref[4];
            #pragma unroll
            for (int ch = 0; ch < 4; ch++)
                vpref[ch] = *(const float4*)&vbase[(size_t)(k0 + lr) * HD + lc + ch * 32];

            float acc[4][2] = {};
            #pragma unroll 4
            for (int d0 = 0; d0 < HD; d0 += 4) {
                float4 ka = *(const float4*)&KV[(j0 + 0) * KVSTR + d0];
                float4 kb4 = *(const float4*)&KV[(j0 + 1) * KVSTR + d0];
                #pragma unroll
                for (int rr = 0; rr < 4; rr++) {
                    float4 q4 = *(const float4*)&Qs[(i0 + rr) * QSTR + d0];
                    acc[rr][0] += q4.x * ka.x + q4.y * ka.y + q4.z * ka.z + q4.w * ka.w;
                    acc[rr][1] += q4.x * kb4.x + q4.y * kb4.y + q4.z * kb4.z + q4.w * kb4.w;
                }
            }

            const bool need_mask = (k0 + ABK - 1) > q0;
            float p[4][2], alpha[4];
            #pragma unroll
            for (int rr = 0; rr < 4; rr++) {
                float z0 = acc[rr][0] * kSc;
                float z1 = acc[rr][1] * kSc;
                if (need_mask) {
                    if (k0 + j0 + 0 > q0 + i0 + rr) z0 = -1e30f;
                    if (k0 + j0 + 1 > q0 + i0 + rr) z1 = -1e30f;
                }
                float rmax = fmaxf(z0, z1);
                #pragma unroll
                for (int off = 1; off < 16; off <<= 1)
                    rmax = fmaxf(rmax, __shfl_xor(rmax, off, 16));
                const float nm = fmaxf(m[rr], rmax);
                alpha[rr] = exp2f(m[rr] - nm);
                p[rr][0] = exp2f(z0 - nm);
                p[rr][1] = exp2f(z1 - nm);
                float ts = p[rr][0] + p[rr][1];
                #pragma unroll
                for (int off = 1; off < 16; off <<= 1)
                    ts += __shfl_xor(ts, off, 16);
                l[rr] = l[rr] * alpha[rr] + ts;
                m[rr] = nm;
            }
            __syncthreads();

            #pragma unroll
            for (int ch = 0; ch < 4; ch++)
                *(float4*)&KV[lr * KVSTR + lc + ch * 32] = vpref[ch];
            *(float4*)&Psf[(j0 + 0) * PSTR + i0] =
                make_float4(p[0][0], p[1][0], p[2][0], p[3][0]);
            *(float4*)&Psf[(j0 + 1) * PSTR + i0] =
                make_float4(p[0][1], p[1][1], p[2][1], p[3][1]);
            if (kt + 1 < ntiles) {
                #pragma unroll
                for (int ch = 0; ch < 4; ch++)
                    kpref[ch] = *(const float4*)&kbase[(size_t)(k0 + ABK + lr) * HD + lc + ch * 32];
            }
            __syncthreads();

            #pragma unroll
            for (int rr = 0; rr < 4; rr++)
                #pragma unroll
                for (int c = 0; c < 8; c++)
                    O[rr][c] *= alpha[rr];
            #pragma unroll 4
            for (int j = 0; j < ABK; j++) {
                float4 pj = *(const float4*)&Psf[j * PSTR + i0];
                float4 v0 = *(const float4*)&KV[j * KVSTR + dd0];
                float4 v1 = *(const float4*)&KV[j * KVSTR + dd0 + 4];
                const float pr[4] = {pj.x, pj.y, pj.z, pj.w};
                const float vv[8] = {v0.x, v0.y, v0.z, v0.w, v1.x, v1.y, v1.z, v1.w};
                #pragma unroll
                for (int rr = 0; rr < 4; rr++)
                    #pragma unroll
                    for (int c = 0; c < 8; c++)
                        O[rr][c] += pr[rr] * vv[c];
            }
            __syncthreads();
        }

        #pragma unroll
        for (int rr = 0; rr < 4; rr++) {
            const float inv = 1.0f / l[rr];
            const int qg = q0 + i0 + rr;
            float4 o0 = make_float4(O[rr][0] * inv, O[rr][1] * inv,
                                    O[rr][2] * inv, O[rr][3] * inv);
            float4 o1 = make_float4(O[rr][4] * inv, O[rr][5] * inv,
                                    O[rr][6] * inv, O[rr][7] * inv);
            float* dst = &ctx[((size_t)qg * H + h) * HD + dd0];
            *(float4*)&dst[0] = o0;
            *(float4*)&dst[4] = o1;
        }
        __syncthreads();
    }
}

__global__ __launch_bounds__(256) void gemm_dense_kernel(
    const float* __restrict__ A, const float* __restrict__ W,
    const float* __restrict__ bias, float* __restrict__ out)
{
    __shared__ float As[16][68];
    __shared__ float Bs[16][64];
    const int bx = blockIdx.x;
    const int by = blockIdx.y;
    const int tid = threadIdx.x;
    const int tx = tid & 15, ty = tid >> 4;
    const int row0 = by * 64, col0 = bx * 64;
    const int am = tid >> 2;
    const int ak = (tid & 3) * 4;
    const int bk = tid >> 4;
    const int bn = (tid & 15) * 4;
    float acc[4][4] = {};
    for (int k0 = 0; k0 < D; k0 += 16) {
        float4 av = *(const float4*)&A[(size_t)(row0 + am) * D + k0 + ak];
        float4 bv = *(const float4*)&W[(size_t)(k0 + bk) * D + col0 + bn];
        __syncthreads();
        As[ak + 0][am] = av.x; As[ak + 1][am] = av.y;
        As[ak + 2][am] = av.z; As[ak + 3][am] = av.w;
        *(float4*)&Bs[bk][bn] = bv;
        __syncthreads();
        #pragma unroll
        for (int k = 0; k < 16; k++) {
            float4 a4 = *(const float4*)&As[k][ty * 4];
            float4 b4 = *(const float4*)&Bs[k][tx * 4];
            float a[4] = {a4.x, a4.y, a4.z, a4.w};
            float b[4] = {b4.x, b4.y, b4.z, b4.w};
            #pragma unroll
            for (int r = 0; r < 4; r++)
                #pragma unroll
                for (int c = 0; c < 4; c++)
                    acc[r][c] += a[r] * b[c];
        }
    }
    const int j0 = col0 + tx * 4;
    const float bv0 = bias[j0 + 0], bv1 = bias[j0 + 1];
    const float bv2 = bias[j0 + 2], bv3 = bias[j0 + 3];
    #pragma unroll
    for (int r = 0; r < 4; r++) {
        const int grow = row0 + ty * 4 + r;
        float4 o4 = make_float4(acc[r][0] + bv0, acc[r][1] + bv1,
                                acc[r][2] + bv2, acc[r][3] + bv3);
        *(float4*)&out[(size_t)grow * D + j0] = o4;
    }
}

extern "C" void kernel_launch(void* const* d_in, const int* in_sizes, int n_in,
                              void* d_out, int out_size, void* d_ws, size_t ws_size,
                              hipStream_t stream) {
    const float* x      = (const float*)d_in[0];
    const float* freqs  = (const float*)d_in[1];
    const int*   pos    = (const int*)d_in[2];
    const float* Wqkv   = (const float*)d_in[3];
    const float* bqkv   = (const float*)d_in[4];
    const float* Wdense = (const float*)d_in[5];
    const float* bdense = (const float*)d_in[6];
    float* out = (float*)d_out;

    const size_t nSD = (size_t)S * D;   // 4 Mi elems
    const size_t nW1 = (size_t)D * N3;  // 12 Mi elems
    const size_t nOP = (size_t)1024 * 64 * 128;   // split-K partial O (f32)
    const size_t nML = (size_t)1024 * 128;        // split-K partial m,l (f32)

    const size_t needed =
        (8 * nSD + 2 * nW1) * sizeof(ushort_t) + (nOP + nML) * sizeof(float);

    if (ws_size >= needed) {
        ushort_t* qh   = (ushort_t*)d_ws;
        ushort_t* kh   = qh + nSD;
        ushort_t* vh   = kh + nSD;
        ushort_t* vl   = vh + nSD;
        ushort_t* ctxh = vl + nSD;
        ushort_t* xh   = ctxh + nSD;
        ushort_t* Wth  = xh + nSD;
        ushort_t* Wtl  = Wth + nW1;
        ushort_t* Wdth = Wtl + nW1;
        ushort_t* Wdtl = Wdth + nSD;
        float* Opart = (float*)(Wdtl + nSD);
        float* MLpart = Opart + nOP;

        convert_hi_kernel<<<nSD / 4 / 256, 256, 0, stream>>>(x, xh);
        dim3 gt1(D / 32, N3 / 32);
        convert_split_t_kernel<<<gt1, 256, 0, stream>>>(Wqkv, Wth, Wtl, D, N3);
        dim3 gt2(D / 32, D / 32);
        convert_split_t_kernel<<<gt2, 256, 0, stream>>>(Wdense, Wdth, Wdtl, D, D);

        dim3 g1(N3 / 128, S / 128);
        gemm_qkv_mfma<<<g1, 256, 0, stream>>>(xh, Wth, Wtl, bqkv, freqs,
                                              pos, qh, kh, vh, vl);
        attn_mfma_kernel<<<1024, 256, 0, stream>>>(qh, kh, vh, vl,
                                                   Opart, MLpart);
        dim3 gc(32, H);
        attn_combine_kernel<<<gc, 128, 0, stream>>>(Opart, MLpart, ctxh);
        dim3 g3(D / 128, S / 128);
        gemm_dense_mfma<<<g3, 256, 0, stream>>>(ctxh, Wdth, Wdtl, bdense, out);
    } else {
        // fallback: R2 f32 path (needs only 64 MiB)
        float* qb  = (float*)d_ws;
        float* kb  = qb + (size_t)H * S * HD;
        float* vb  = kb + (size_t)H * S * HD;
        float* ctx = vb + (size_t)H * S * HD;
        dim3 g1(N3 / 64, S / 64);
        gemm_qkv_kernel<<<g1, 256, 0, stream>>>(x, Wqkv, bqkv, freqs, pos, qb, kb, vb);
        dim3 g2(16, H);
        attn_kernel<<<g2, 256, 0, stream>>>(qb, kb, vb, ctx);
        dim3 g3(D / 64, S / 64);
        gemm_dense_kernel<<<g3, 256, 0, stream>>>(ctx, Wdense, bdense, out);
    }
}